// Round 2
// baseline (569.892 us; speedup 1.0000x reference)
//
#include <hip/hip_runtime.h>

typedef _Float16 half8 __attribute__((ext_vector_type(8)));
typedef _Float16 half4 __attribute__((ext_vector_type(4)));
typedef float    floatx4 __attribute__((ext_vector_type(4)));
typedef float    float4v __attribute__((ext_vector_type(4)));

#define BB 8
#define NN 2048
#define DD 512

// MFMA fragment mapping (gfx950, 16x16x32, m89/m91/m120-verified):
//   A-operand: A[m = lane&15][k = (lane>>4)*8 + j], j=0..7 contiguous
//   B-operand: B[n = lane&15][k = (lane>>4)*8 + j]   (NT: both contiguous in k)
//   C/D:       col = lane&15, row = (lane>>4)*4 + reg

// ---------------------------------------------------------------------------
// Kernel 1: QKV projection.  q/k: plain fp16 (logit error ~1e-3 through
// softmax, within budget).  v: 3-product hi/lo split (x=xh+xl, W=Wh+Wl;
// hh+hl+lh) -> fp32-accurate v, stored as fp16 hi+lo pair for the PV MFMA.
// C[m][e] = sum_d x[m][d] * W[e][d]   (NT GEMM, K=512)
// ---------------------------------------------------------------------------
__global__ __launch_bounds__(256) void proj_kernel(
    const float* __restrict__ x,
    const float* __restrict__ Wq, const float* __restrict__ bq,
    const float* __restrict__ Wk, const float* __restrict__ bk,
    const float* __restrict__ Wv, const float* __restrict__ bv,
    _Float16* __restrict__ qb, _Float16* __restrict__ kb,
    _Float16* __restrict__ vhi, _Float16* __restrict__ vlo)
{
    const int z = blockIdx.z;                       // 0=q 1=k 2=v
    const float* W    = (z == 0) ? Wq : (z == 1) ? Wk : Wv;
    const float* bias = (z == 0) ? bq : (z == 1) ? bk : bv;
    const int r0 = blockIdx.y * 128;                // x-row tile [0,16384)
    const int c0 = blockIdx.x * 128;                // out-col tile [0,512)
    const bool split = (z == 2);

    __shared__ __align__(16) _Float16 As[2][128][40];   // +8 pad: bank spread
    __shared__ __align__(16) _Float16 Bs[2][128][40];

    const int tid  = threadIdx.x;
    const int lane = tid & 63;
    const int w    = tid >> 6;
    const int wm   = w >> 1, wn = w & 1;
    const int lr   = lane & 15;
    const int quad = lane >> 4;
    const int koff = quad * 8;

    floatx4 zero; zero[0]=0.f; zero[1]=0.f; zero[2]=0.f; zero[3]=0.f;
    floatx4 acc[4][4];
    for (int i = 0; i < 4; ++i)
        for (int j = 0; j < 4; ++j) acc[i][j] = zero;

    for (int kt = 0; kt < DD / 32; ++kt) {
        __syncthreads();
        // stage 128x32 fp32 tiles of x and W -> fp16 (hi[,lo]) in LDS
        for (int i = 0; i < 4; ++i) {
            int c   = tid + i * 256;        // 0..1023
            int row = c >> 3;               // 0..127
            int kc  = (c & 7) * 4;          // 0..28
            float4v fa = *(const float4v*)&x[(size_t)(r0 + row) * DD + kt * 32 + kc];
            float4v fb = *(const float4v*)&W[(size_t)(c0 + row) * DD + kt * 32 + kc];
            half4 ha, hb;
            for (int j = 0; j < 4; ++j) { ha[j] = (_Float16)fa[j]; hb[j] = (_Float16)fb[j]; }
            *(half4*)&As[0][row][kc] = ha;
            *(half4*)&Bs[0][row][kc] = hb;
            if (split) {
                half4 la, lb;
                for (int j = 0; j < 4; ++j) {
                    la[j] = (_Float16)(fa[j] - (float)ha[j]);
                    lb[j] = (_Float16)(fb[j] - (float)hb[j]);
                }
                *(half4*)&As[1][row][kc] = la;
                *(half4*)&Bs[1][row][kc] = lb;
            }
        }
        __syncthreads();

        half8 ah[4], al[4], bh[4], bl[4];
        for (int mt = 0; mt < 4; ++mt) {
            int m = wm * 64 + mt * 16 + lr;
            ah[mt] = *(const half8*)&As[0][m][koff];
            if (split) al[mt] = *(const half8*)&As[1][m][koff];
        }
        for (int nt = 0; nt < 4; ++nt) {
            int n = wn * 64 + nt * 16 + lr;
            bh[nt] = *(const half8*)&Bs[0][n][koff];
            if (split) bl[nt] = *(const half8*)&Bs[1][n][koff];
        }
        if (!split) {
            for (int mt = 0; mt < 4; ++mt)
                for (int nt = 0; nt < 4; ++nt)
                    acc[mt][nt] = __builtin_amdgcn_mfma_f32_16x16x32_f16(ah[mt], bh[nt], acc[mt][nt], 0, 0, 0);
        } else {
            for (int mt = 0; mt < 4; ++mt)
                for (int nt = 0; nt < 4; ++nt) {
                    acc[mt][nt] = __builtin_amdgcn_mfma_f32_16x16x32_f16(ah[mt], bh[nt], acc[mt][nt], 0, 0, 0);
                    acc[mt][nt] = __builtin_amdgcn_mfma_f32_16x16x32_f16(ah[mt], bl[nt], acc[mt][nt], 0, 0, 0);
                    acc[mt][nt] = __builtin_amdgcn_mfma_f32_16x16x32_f16(al[mt], bh[nt], acc[mt][nt], 0, 0, 0);
                }
        }
    }

    for (int mt = 0; mt < 4; ++mt)
        for (int nt = 0; nt < 4; ++nt)
            for (int r = 0; r < 4; ++r) {
                int row = r0 + wm * 64 + mt * 16 + quad * 4 + r;
                int col = c0 + wn * 64 + nt * 16 + lr;
                float v = acc[mt][nt][r] + bias[col];
                size_t idx = (size_t)row * DD + col;
                if (z == 0) qb[idx] = (_Float16)v;
                else if (z == 1) kb[idx] = (_Float16)v;
                else {
                    _Float16 h = (_Float16)v;
                    vhi[idx] = h;
                    vlo[idx] = (_Float16)(v - (float)h);
                }
            }
}

// ---------------------------------------------------------------------------
// Kernel 2: S[b][q][k] = (Q[b] . K[b]^T) * 1/sqrt(512), masked -> fp16.
// Mask semantics match ref: valid iff (q<L && k<L), else sentinel -30000
// (identical fp16 value everywhere -> uniform softmax for rows q>=L, exact
// underflow-to-0 for masked keys of valid rows).
// ---------------------------------------------------------------------------
__global__ __launch_bounds__(256) void scores_kernel(
    const _Float16* __restrict__ qb, const _Float16* __restrict__ kb,
    const int* __restrict__ lens, _Float16* __restrict__ S)
{
    const int b  = blockIdx.z;
    const int r0 = blockIdx.y * 128;   // q rows
    const int c0 = blockIdx.x * 128;   // key cols
    const _Float16* A  = qb + (size_t)b * NN * DD;
    const _Float16* Bm = kb + (size_t)b * NN * DD;

    __shared__ __align__(16) _Float16 As[128][40];
    __shared__ __align__(16) _Float16 Bs[128][40];

    const int tid  = threadIdx.x;
    const int lane = tid & 63;
    const int w    = tid >> 6;
    const int wm   = w >> 1, wn = w & 1;
    const int lr   = lane & 15;
    const int quad = lane >> 4;
    const int koff = quad * 8;

    floatx4 zero; zero[0]=0.f; zero[1]=0.f; zero[2]=0.f; zero[3]=0.f;
    floatx4 acc[4][4];
    for (int i = 0; i < 4; ++i)
        for (int j = 0; j < 4; ++j) acc[i][j] = zero;

    for (int kt = 0; kt < DD / 32; ++kt) {
        __syncthreads();
        for (int i = 0; i < 2; ++i) {
            int c   = tid + i * 256;       // 0..511
            int row = c >> 2;              // 0..127
            int kc  = (c & 3) * 8;         // 0..24
            *(half8*)&As[row][kc] = *(const half8*)&A [(size_t)(r0 + row) * DD + kt * 32 + kc];
            *(half8*)&Bs[row][kc] = *(const half8*)&Bm[(size_t)(c0 + row) * DD + kt * 32 + kc];
        }
        __syncthreads();
        half8 a[4], bfr[4];
        for (int mt = 0; mt < 4; ++mt) a[mt]   = *(const half8*)&As[wm * 64 + mt * 16 + lr][koff];
        for (int nt = 0; nt < 4; ++nt) bfr[nt] = *(const half8*)&Bs[wn * 64 + nt * 16 + lr][koff];
        for (int mt = 0; mt < 4; ++mt)
            for (int nt = 0; nt < 4; ++nt)
                acc[mt][nt] = __builtin_amdgcn_mfma_f32_16x16x32_f16(a[mt], bfr[nt], acc[mt][nt], 0, 0, 0);
    }

    const int L = lens[b];
    const float scale = 0.044194173824159216f;   // 1/sqrt(512)
    const _Float16 sentinel = (_Float16)(-30000.0f);
    for (int mt = 0; mt < 4; ++mt)
        for (int nt = 0; nt < 4; ++nt)
            for (int r = 0; r < 4; ++r) {
                int q    = r0 + wm * 64 + mt * 16 + quad * 4 + r;
                int kcol = c0 + wn * 64 + nt * 16 + lr;
                float s  = acc[mt][nt][r] * scale;
                _Float16 o = (q < L && kcol < L) ? (_Float16)s : sentinel;
                S[((size_t)b * NN + q) * NN + kcol] = o;
            }
}

// ---------------------------------------------------------------------------
// Kernel 3: in-place row softmax on S (fp16), fp32 math.  One block per row;
// each block owns its row exclusively so in-place is race-free.
// ---------------------------------------------------------------------------
__global__ __launch_bounds__(256) void softmax_kernel(_Float16* __restrict__ S)
{
    const size_t base = ((size_t)blockIdx.y * NN + blockIdx.x) * NN;
    const int tid  = threadIdx.x;
    const int lane = tid & 63;
    const int w    = tid >> 6;

    half8 v = *(const half8*)&S[base + tid * 8];
    float f[8];
    for (int j = 0; j < 8; ++j) f[j] = (float)v[j];

    float m = f[0];
    for (int j = 1; j < 8; ++j) m = fmaxf(m, f[j]);
    for (int off = 32; off > 0; off >>= 1) m = fmaxf(m, __shfl_xor(m, off));
    __shared__ float redm[4];
    __shared__ float reds[4];
    if (lane == 0) redm[w] = m;
    __syncthreads();
    m = fmaxf(fmaxf(redm[0], redm[1]), fmaxf(redm[2], redm[3]));

    float e[8], s = 0.f;
    for (int j = 0; j < 8; ++j) { e[j] = __expf(f[j] - m); s += e[j]; }
    for (int off = 32; off > 0; off >>= 1) s += __shfl_xor(s, off);
    if (lane == 0) reds[w] = s;
    __syncthreads();
    s = (reds[0] + reds[1]) + (reds[2] + reds[3]);

    float inv = 1.0f / s;
    half8 o;
    for (int j = 0; j < 8; ++j) o[j] = (_Float16)(e[j] * inv);
    *(half8*)&S[base + tid * 8] = o;
}

// ---------------------------------------------------------------------------
// Kernel 4: O[b][q][e] = sum_k P[b][q][k] * V[b][k][e],  V = vhi + vlo
// (2 MFMAs per fragment -> v rounding error eliminated).  V staged into LDS
// transposed so the B-fragment reads are contiguous in k.
// ---------------------------------------------------------------------------
__global__ __launch_bounds__(256) void pv_kernel(
    const _Float16* __restrict__ P, const _Float16* __restrict__ vhi,
    const _Float16* __restrict__ vlo, float* __restrict__ out)
{
    const int b  = blockIdx.z;
    const int r0 = blockIdx.y * 128;   // q rows
    const int c0 = blockIdx.x * 128;   // e cols (512/128 = 4 tiles)
    const _Float16* A  = P   + (size_t)b * NN * NN;
    const _Float16* Vh = vhi + (size_t)b * NN * DD;
    const _Float16* Vl = vlo + (size_t)b * NN * DD;

    __shared__ __align__(16) _Float16 As[128][40];
    __shared__ __align__(16) _Float16 Bh[128][40];
    __shared__ __align__(16) _Float16 Bl[128][40];

    const int tid  = threadIdx.x;
    const int lane = tid & 63;
    const int w    = tid >> 6;
    const int wm   = w >> 1, wn = w & 1;
    const int lr   = lane & 15;
    const int quad = lane >> 4;
    const int koff = quad * 8;

    floatx4 zero; zero[0]=0.f; zero[1]=0.f; zero[2]=0.f; zero[3]=0.f;
    floatx4 acc[4][4];
    for (int i = 0; i < 4; ++i)
        for (int j = 0; j < 4; ++j) acc[i][j] = zero;

    for (int kt = 0; kt < NN / 32; ++kt) {
        __syncthreads();
        // A: P rows, k contiguous
        for (int i = 0; i < 2; ++i) {
            int c   = tid + i * 256;
            int row = c >> 2;
            int kc  = (c & 3) * 8;
            *(half8*)&As[row][kc] = *(const half8*)&A[(size_t)(r0 + row) * NN + kt * 32 + kc];
        }
        // B: V[k][e] -> LDS transposed [e_local][k_local]
        for (int i = 0; i < 2; ++i) {
            int c  = tid + i * 256;
            int kr = c >> 4;             // 0..31
            int nc = (c & 15) * 8;       // 0..120
            half8 vh = *(const half8*)&Vh[(size_t)(kt * 32 + kr) * DD + c0 + nc];
            half8 vl = *(const half8*)&Vl[(size_t)(kt * 32 + kr) * DD + c0 + nc];
            for (int j = 0; j < 8; ++j) { Bh[nc + j][kr] = vh[j]; Bl[nc + j][kr] = vl[j]; }
        }
        __syncthreads();

        half8 a[4], bh[4], bl[4];
        for (int mt = 0; mt < 4; ++mt) a[mt]  = *(const half8*)&As[wm * 64 + mt * 16 + lr][koff];
        for (int nt = 0; nt < 4; ++nt) {
            bh[nt] = *(const half8*)&Bh[wn * 64 + nt * 16 + lr][koff];
            bl[nt] = *(const half8*)&Bl[wn * 64 + nt * 16 + lr][koff];
        }
        for (int mt = 0; mt < 4; ++mt)
            for (int nt = 0; nt < 4; ++nt) {
                acc[mt][nt] = __builtin_amdgcn_mfma_f32_16x16x32_f16(a[mt], bh[nt], acc[mt][nt], 0, 0, 0);
                acc[mt][nt] = __builtin_amdgcn_mfma_f32_16x16x32_f16(a[mt], bl[nt], acc[mt][nt], 0, 0, 0);
            }
    }

    for (int mt = 0; mt < 4; ++mt)
        for (int nt = 0; nt < 4; ++nt)
            for (int r = 0; r < 4; ++r) {
                int q = r0 + wm * 64 + mt * 16 + quad * 4 + r;
                int e = c0 + wn * 64 + nt * 16 + lr;
                out[((size_t)b * NN + q) * DD + e] = acc[mt][nt][r];
            }
}

// ---------------------------------------------------------------------------
extern "C" void kernel_launch(void* const* d_in, const int* in_sizes, int n_in,
                              void* d_out, int out_size, void* d_ws, size_t ws_size,
                              hipStream_t stream) {
    const float* x    = (const float*)d_in[0];
    const int*   lens = (const int*)d_in[1];   // harness delivers integer inputs as int32
    const float* Wq   = (const float*)d_in[2];
    const float* bq   = (const float*)d_in[3];
    const float* Wk   = (const float*)d_in[4];
    const float* bk   = (const float*)d_in[5];
    const float* Wv   = (const float*)d_in[6];
    const float* bv   = (const float*)d_in[7];
    float* out = (float*)d_out;

    // workspace layout (128 MiB total):
    //   qb 16M | kb 16M | vhi 16M | vlo 16M | S/P (in-place) 64M
    char* ws = (char*)d_ws;
    const size_t MB = 1024 * 1024;
    _Float16* qb  = (_Float16*)(ws);
    _Float16* kb  = (_Float16*)(ws + 16 * MB);
    _Float16* vh  = (_Float16*)(ws + 32 * MB);
    _Float16* vl  = (_Float16*)(ws + 48 * MB);
    _Float16* S   = (_Float16*)(ws + 64 * MB);

    proj_kernel  <<<dim3(4, 128, 3), 256, 0, stream>>>(x, Wq, bq, Wk, bk, Wv, bv, qb, kb, vh, vl);
    scores_kernel<<<dim3(16, 16, 8), 256, 0, stream>>>(qb, kb, lens, S);
    softmax_kernel<<<dim3(2048, 8, 1), 256, 0, stream>>>(S);
    pv_kernel    <<<dim3(4, 16, 8), 256, 0, stream>>>(S, vh, vl, out);
}

// Round 3
// 334.417 us; speedup vs baseline: 1.7041x; 1.7041x over previous
//
#include <hip/hip_runtime.h>

typedef _Float16 half8 __attribute__((ext_vector_type(8)));
typedef _Float16 half4 __attribute__((ext_vector_type(4)));
typedef float    floatx4 __attribute__((ext_vector_type(4)));
typedef float    float4v __attribute__((ext_vector_type(4)));

#define BB 8
#define NN 2048
#define DD 512

// MFMA fragment mapping (gfx950, 16x16x32, m89/m91/m120-verified):
//   A-operand: A[m = lane&15][k = (lane>>4)*8 + j], j=0..7 contiguous
//   B-operand: B[n = lane&15][k = (lane>>4)*8 + j]   (NT: both contiguous in k)
//   C/D:       col = lane&15, row = (lane>>4)*4 + reg

// ---------------------------------------------------------------------------
// Kernel 1: Q/K projection (plain fp16; logit error ~1e-3 through softmax,
// within budget).  C[m][e] = sum_d x[m][d] * W[e][d]   (NT GEMM, K=512)
// ---------------------------------------------------------------------------
__global__ __launch_bounds__(256) void proj_kernel(
    const float* __restrict__ x,
    const float* __restrict__ Wq, const float* __restrict__ bq,
    const float* __restrict__ Wk, const float* __restrict__ bk,
    _Float16* __restrict__ qb, _Float16* __restrict__ kb)
{
    const int z = blockIdx.z;                       // 0=q 1=k
    const float* W    = (z == 0) ? Wq : Wk;
    const float* bias = (z == 0) ? bq : bk;
    const int r0 = blockIdx.y * 128;                // x-row tile [0,16384)
    const int c0 = blockIdx.x * 128;                // out-col tile [0,512)

    __shared__ __align__(16) _Float16 As[128][40];  // +8 pad: bank spread
    __shared__ __align__(16) _Float16 Bs[128][40];

    const int tid  = threadIdx.x;
    const int lane = tid & 63;
    const int w    = tid >> 6;
    const int wm   = w >> 1, wn = w & 1;
    const int lr   = lane & 15;
    const int quad = lane >> 4;
    const int koff = quad * 8;

    floatx4 zero; zero[0]=0.f; zero[1]=0.f; zero[2]=0.f; zero[3]=0.f;
    floatx4 acc[4][4];
    for (int i = 0; i < 4; ++i)
        for (int j = 0; j < 4; ++j) acc[i][j] = zero;

    for (int kt = 0; kt < DD / 32; ++kt) {
        __syncthreads();
        for (int i = 0; i < 4; ++i) {
            int c   = tid + i * 256;        // 0..1023
            int row = c >> 3;               // 0..127
            int kc  = (c & 7) * 4;          // 0..28
            float4v fa = *(const float4v*)&x[(size_t)(r0 + row) * DD + kt * 32 + kc];
            float4v fb = *(const float4v*)&W[(size_t)(c0 + row) * DD + kt * 32 + kc];
            half4 ha, hb;
            for (int j = 0; j < 4; ++j) { ha[j] = (_Float16)fa[j]; hb[j] = (_Float16)fb[j]; }
            *(half4*)&As[row][kc] = ha;
            *(half4*)&Bs[row][kc] = hb;
        }
        __syncthreads();

        half8 ah[4], bh[4];
        for (int mt = 0; mt < 4; ++mt) ah[mt] = *(const half8*)&As[wm * 64 + mt * 16 + lr][koff];
        for (int nt = 0; nt < 4; ++nt) bh[nt] = *(const half8*)&Bs[wn * 64 + nt * 16 + lr][koff];
        for (int mt = 0; mt < 4; ++mt)
            for (int nt = 0; nt < 4; ++nt)
                acc[mt][nt] = __builtin_amdgcn_mfma_f32_16x16x32_f16(ah[mt], bh[nt], acc[mt][nt], 0, 0, 0);
    }

    for (int mt = 0; mt < 4; ++mt)
        for (int nt = 0; nt < 4; ++nt)
            for (int r = 0; r < 4; ++r) {
                int row = r0 + wm * 64 + mt * 16 + quad * 4 + r;
                int col = c0 + wn * 64 + nt * 16 + lr;
                float v = acc[mt][nt][r] + bias[col];
                size_t idx = (size_t)row * DD + col;
                if (z == 0) qb[idx] = (_Float16)v;
                else        kb[idx] = (_Float16)v;
            }
}

// ---------------------------------------------------------------------------
// Kernel 1b: V projection, TRANSPOSED output.  Vt[b][e][n] = sum_d
// Wv[e][d] * x[b,n][d]  (swap A/B operands -> C rows are e, cols are n; the
// C/D col dim (lane&15) is contiguous n -> coalesced-enough stores, and pv
// can then stage V^T with vectorized conflict-free LDS writes).
// 3-product hi/lo split (hh + hl + lh) -> fp32-accurate v, stored as fp16
// hi+lo pair for the PV MFMA.
// ---------------------------------------------------------------------------
__global__ __launch_bounds__(256) void projv_kernel(
    const float* __restrict__ x,
    const float* __restrict__ Wv, const float* __restrict__ bv,
    _Float16* __restrict__ vhT, _Float16* __restrict__ vlT)
{
    const int b  = blockIdx.z;
    const int e0 = blockIdx.y * 128;   // 4 tiles over D=512 (rows of Vt)
    const int n0 = blockIdx.x * 128;   // 16 tiles over N=2048 (cols of Vt)

    __shared__ __align__(16) _Float16 As[2][128][40];   // Wv hi/lo
    __shared__ __align__(16) _Float16 Bs[2][128][40];   // x  hi/lo

    const int tid  = threadIdx.x;
    const int lane = tid & 63;
    const int w    = tid >> 6;
    const int wm   = w >> 1, wn = w & 1;
    const int lr   = lane & 15;
    const int quad = lane >> 4;
    const int koff = quad * 8;

    floatx4 zero; zero[0]=0.f; zero[1]=0.f; zero[2]=0.f; zero[3]=0.f;
    floatx4 acc[4][4];
    for (int i = 0; i < 4; ++i)
        for (int j = 0; j < 4; ++j) acc[i][j] = zero;

    for (int kt = 0; kt < DD / 32; ++kt) {
        __syncthreads();
        for (int i = 0; i < 4; ++i) {
            int c   = tid + i * 256;        // 0..1023
            int row = c >> 3;               // 0..127
            int kc  = (c & 7) * 4;          // 0..28
            float4v fa = *(const float4v*)&Wv[(size_t)(e0 + row) * DD + kt * 32 + kc];
            float4v fb = *(const float4v*)&x[((size_t)b * NN + n0 + row) * DD + kt * 32 + kc];
            half4 ha, hb, la, lb;
            for (int j = 0; j < 4; ++j) {
                ha[j] = (_Float16)fa[j];  la[j] = (_Float16)(fa[j] - (float)ha[j]);
                hb[j] = (_Float16)fb[j];  lb[j] = (_Float16)(fb[j] - (float)hb[j]);
            }
            *(half4*)&As[0][row][kc] = ha;
            *(half4*)&As[1][row][kc] = la;
            *(half4*)&Bs[0][row][kc] = hb;
            *(half4*)&Bs[1][row][kc] = lb;
        }
        __syncthreads();

        half8 ah[4], al[4], bh[4], bl[4];
        for (int mt = 0; mt < 4; ++mt) {
            int m = wm * 64 + mt * 16 + lr;
            ah[mt] = *(const half8*)&As[0][m][koff];
            al[mt] = *(const half8*)&As[1][m][koff];
        }
        for (int nt = 0; nt < 4; ++nt) {
            int n = wn * 64 + nt * 16 + lr;
            bh[nt] = *(const half8*)&Bs[0][n][koff];
            bl[nt] = *(const half8*)&Bs[1][n][koff];
        }
        for (int mt = 0; mt < 4; ++mt)
            for (int nt = 0; nt < 4; ++nt) {
                acc[mt][nt] = __builtin_amdgcn_mfma_f32_16x16x32_f16(ah[mt], bh[nt], acc[mt][nt], 0, 0, 0);
                acc[mt][nt] = __builtin_amdgcn_mfma_f32_16x16x32_f16(ah[mt], bl[nt], acc[mt][nt], 0, 0, 0);
                acc[mt][nt] = __builtin_amdgcn_mfma_f32_16x16x32_f16(al[mt], bh[nt], acc[mt][nt], 0, 0, 0);
            }
    }

    for (int mt = 0; mt < 4; ++mt)
        for (int nt = 0; nt < 4; ++nt)
            for (int r = 0; r < 4; ++r) {
                int e = e0 + wm * 64 + mt * 16 + quad * 4 + r;   // row of Vt
                int n = n0 + wn * 64 + nt * 16 + lr;             // col of Vt
                float v = acc[mt][nt][r] + bv[e];
                size_t idx = ((size_t)b * DD + e) * NN + n;
                _Float16 h = (_Float16)v;
                vhT[idx] = h;
                vlT[idx] = (_Float16)(v - (float)h);
            }
}

// ---------------------------------------------------------------------------
// Kernel 2: S[b][q][k] = (Q[b] . K[b]^T) * 1/sqrt(512), masked -> fp16.
// Mask: valid iff (q<L && k<L), else sentinel -30000 (identical fp16 value
// everywhere -> uniform softmax for rows q>=L, underflow-to-0 for masked
// keys of valid rows) — matches ref semantics.
// ---------------------------------------------------------------------------
__global__ __launch_bounds__(256) void scores_kernel(
    const _Float16* __restrict__ qb, const _Float16* __restrict__ kb,
    const int* __restrict__ lens, _Float16* __restrict__ S)
{
    const int b  = blockIdx.z;
    const int r0 = blockIdx.y * 128;   // q rows
    const int c0 = blockIdx.x * 128;   // key cols
    const _Float16* A  = qb + (size_t)b * NN * DD;
    const _Float16* Bm = kb + (size_t)b * NN * DD;

    __shared__ __align__(16) _Float16 As[128][40];
    __shared__ __align__(16) _Float16 Bs[128][40];

    const int tid  = threadIdx.x;
    const int lane = tid & 63;
    const int w    = tid >> 6;
    const int wm   = w >> 1, wn = w & 1;
    const int lr   = lane & 15;
    const int quad = lane >> 4;
    const int koff = quad * 8;

    floatx4 zero; zero[0]=0.f; zero[1]=0.f; zero[2]=0.f; zero[3]=0.f;
    floatx4 acc[4][4];
    for (int i = 0; i < 4; ++i)
        for (int j = 0; j < 4; ++j) acc[i][j] = zero;

    for (int kt = 0; kt < DD / 32; ++kt) {
        __syncthreads();
        for (int i = 0; i < 2; ++i) {
            int c   = tid + i * 256;       // 0..511
            int row = c >> 2;              // 0..127
            int kc  = (c & 3) * 8;         // 0..24
            *(half8*)&As[row][kc] = *(const half8*)&A [(size_t)(r0 + row) * DD + kt * 32 + kc];
            *(half8*)&Bs[row][kc] = *(const half8*)&Bm[(size_t)(c0 + row) * DD + kt * 32 + kc];
        }
        __syncthreads();
        half8 a[4], bfr[4];
        for (int mt = 0; mt < 4; ++mt) a[mt]   = *(const half8*)&As[wm * 64 + mt * 16 + lr][koff];
        for (int nt = 0; nt < 4; ++nt) bfr[nt] = *(const half8*)&Bs[wn * 64 + nt * 16 + lr][koff];
        for (int mt = 0; mt < 4; ++mt)
            for (int nt = 0; nt < 4; ++nt)
                acc[mt][nt] = __builtin_amdgcn_mfma_f32_16x16x32_f16(a[mt], bfr[nt], acc[mt][nt], 0, 0, 0);
    }

    const int L = lens[b];
    const float scale = 0.044194173824159216f;   // 1/sqrt(512)
    const _Float16 sentinel = (_Float16)(-30000.0f);
    for (int mt = 0; mt < 4; ++mt)
        for (int nt = 0; nt < 4; ++nt)
            for (int r = 0; r < 4; ++r) {
                int q    = r0 + wm * 64 + mt * 16 + quad * 4 + r;
                int kcol = c0 + wn * 64 + nt * 16 + lr;
                float s  = acc[mt][nt][r] * scale;
                _Float16 o = (q < L && kcol < L) ? (_Float16)s : sentinel;
                S[((size_t)b * NN + q) * NN + kcol] = o;
            }
}

// ---------------------------------------------------------------------------
// Kernel 3: in-place row softmax on S (fp16), fp32 math.  One block per row.
// ---------------------------------------------------------------------------
__global__ __launch_bounds__(256) void softmax_kernel(_Float16* __restrict__ S)
{
    const size_t base = ((size_t)blockIdx.y * NN + blockIdx.x) * NN;
    const int tid  = threadIdx.x;
    const int lane = tid & 63;
    const int w    = tid >> 6;

    half8 v = *(const half8*)&S[base + tid * 8];
    float f[8];
    for (int j = 0; j < 8; ++j) f[j] = (float)v[j];

    float m = f[0];
    for (int j = 1; j < 8; ++j) m = fmaxf(m, f[j]);
    for (int off = 32; off > 0; off >>= 1) m = fmaxf(m, __shfl_xor(m, off));
    __shared__ float redm[4];
    __shared__ float reds[4];
    if (lane == 0) redm[w] = m;
    __syncthreads();
    m = fmaxf(fmaxf(redm[0], redm[1]), fmaxf(redm[2], redm[3]));

    float e[8], s = 0.f;
    for (int j = 0; j < 8; ++j) { e[j] = __expf(f[j] - m); s += e[j]; }
    for (int off = 32; off > 0; off >>= 1) s += __shfl_xor(s, off);
    if (lane == 0) reds[w] = s;
    __syncthreads();
    s = (reds[0] + reds[1]) + (reds[2] + reds[3]);

    float inv = 1.0f / s;
    half8 o;
    for (int j = 0; j < 8; ++j) o[j] = (_Float16)(e[j] * inv);
    *(half8*)&S[base + tid * 8] = o;
}

// ---------------------------------------------------------------------------
// Kernel 4: O[b][q][e] = sum_k P[b][q][k] * Vt[b][e][k],  V = vhi + vlo.
// Vt is pre-transposed so B-staging is vectorized half8 -> conflict-free LDS
// (same pattern as scores_kernel; <=2-way bank aliasing = free per m136).
// ---------------------------------------------------------------------------
__global__ __launch_bounds__(256) void pv_kernel(
    const _Float16* __restrict__ P, const _Float16* __restrict__ vhT,
    const _Float16* __restrict__ vlT, float* __restrict__ out)
{
    const int b  = blockIdx.z;
    const int r0 = blockIdx.y * 128;   // q rows
    const int c0 = blockIdx.x * 128;   // e cols (512/128 = 4 tiles)
    const _Float16* A  = P   + (size_t)b * NN * NN;
    const _Float16* Vh = vhT + (size_t)b * DD * NN;
    const _Float16* Vl = vlT + (size_t)b * DD * NN;

    __shared__ __align__(16) _Float16 As[128][40];
    __shared__ __align__(16) _Float16 Bh[128][40];
    __shared__ __align__(16) _Float16 Bl[128][40];

    const int tid  = threadIdx.x;
    const int lane = tid & 63;
    const int w    = tid >> 6;
    const int wm   = w >> 1, wn = w & 1;
    const int lr   = lane & 15;
    const int quad = lane >> 4;
    const int koff = quad * 8;

    floatx4 zero; zero[0]=0.f; zero[1]=0.f; zero[2]=0.f; zero[3]=0.f;
    floatx4 acc[4][4];
    for (int i = 0; i < 4; ++i)
        for (int j = 0; j < 4; ++j) acc[i][j] = zero;

    for (int kt = 0; kt < NN / 32; ++kt) {
        __syncthreads();
        for (int i = 0; i < 2; ++i) {
            int c   = tid + i * 256;
            int row = c >> 2;              // 0..127
            int kc  = (c & 3) * 8;         // 0..24
            size_t goff = (size_t)(c0 + row) * NN + kt * 32 + kc;
            *(half8*)&As[row][kc] = *(const half8*)&A[(size_t)(r0 + row) * NN + kt * 32 + kc];
            *(half8*)&Bh[row][kc] = *(const half8*)&Vh[goff];
            *(half8*)&Bl[row][kc] = *(const half8*)&Vl[goff];
        }
        __syncthreads();

        half8 a[4], bh[4], bl[4];
        for (int mt = 0; mt < 4; ++mt) a[mt]  = *(const half8*)&As[wm * 64 + mt * 16 + lr][koff];
        for (int nt = 0; nt < 4; ++nt) {
            bh[nt] = *(const half8*)&Bh[wn * 64 + nt * 16 + lr][koff];
            bl[nt] = *(const half8*)&Bl[wn * 64 + nt * 16 + lr][koff];
        }
        for (int mt = 0; mt < 4; ++mt)
            for (int nt = 0; nt < 4; ++nt) {
                acc[mt][nt] = __builtin_amdgcn_mfma_f32_16x16x32_f16(a[mt], bh[nt], acc[mt][nt], 0, 0, 0);
                acc[mt][nt] = __builtin_amdgcn_mfma_f32_16x16x32_f16(a[mt], bl[nt], acc[mt][nt], 0, 0, 0);
            }
    }

    for (int mt = 0; mt < 4; ++mt)
        for (int nt = 0; nt < 4; ++nt)
            for (int r = 0; r < 4; ++r) {
                int q = r0 + wm * 64 + mt * 16 + quad * 4 + r;
                int e = c0 + wn * 64 + nt * 16 + lr;
                out[((size_t)b * NN + q) * DD + e] = acc[mt][nt][r];
            }
}

// ---------------------------------------------------------------------------
extern "C" void kernel_launch(void* const* d_in, const int* in_sizes, int n_in,
                              void* d_out, int out_size, void* d_ws, size_t ws_size,
                              hipStream_t stream) {
    const float* x    = (const float*)d_in[0];
    const int*   lens = (const int*)d_in[1];   // harness delivers integer inputs as int32
    const float* Wq   = (const float*)d_in[2];
    const float* bq   = (const float*)d_in[3];
    const float* Wk   = (const float*)d_in[4];
    const float* bk   = (const float*)d_in[5];
    const float* Wv   = (const float*)d_in[6];
    const float* bv   = (const float*)d_in[7];
    float* out = (float*)d_out;

    // workspace layout (128 MiB total):
    //   qb 16M | kb 16M | vhT 16M | vlT 16M | S/P (in-place) 64M
    char* ws = (char*)d_ws;
    const size_t MB = 1024 * 1024;
    _Float16* qb  = (_Float16*)(ws);
    _Float16* kb  = (_Float16*)(ws + 16 * MB);
    _Float16* vh  = (_Float16*)(ws + 32 * MB);
    _Float16* vl  = (_Float16*)(ws + 48 * MB);
    _Float16* S   = (_Float16*)(ws + 64 * MB);

    proj_kernel  <<<dim3(4, 128, 2), 256, 0, stream>>>(x, Wq, bq, Wk, bk, qb, kb);
    projv_kernel <<<dim3(16, 4, 8),  256, 0, stream>>>(x, Wv, bv, vh, vl);
    scores_kernel<<<dim3(16, 16, 8), 256, 0, stream>>>(qb, kb, lens, S);
    softmax_kernel<<<dim3(2048, 8, 1), 256, 0, stream>>>(S);
    pv_kernel    <<<dim3(4, 16, 8),  256, 0, stream>>>(S, vh, vl, out);
}

// Round 4
// 315.873 us; speedup vs baseline: 1.8042x; 1.0587x over previous
//
#include <hip/hip_runtime.h>

typedef _Float16 half8 __attribute__((ext_vector_type(8)));
typedef _Float16 half4 __attribute__((ext_vector_type(4)));
typedef float    floatx4 __attribute__((ext_vector_type(4)));
typedef float    float4v __attribute__((ext_vector_type(4)));

#define BB 8
#define NN 2048
#define DD 512

// MFMA fragment mapping (gfx950, 16x16x32, m89/m91/m120-verified):
//   A-operand: A[m = lane&15][k = (lane>>4)*8 + j], j=0..7 contiguous
//   B-operand: B[n = lane&15][k = (lane>>4)*8 + j]   (NT: both contiguous in k)
//   C/D:       col = lane&15, row = (lane>>4)*4 + reg
//
// m97-style staging: unpadded [128][32] fp16 LDS tiles filled by
// global_load_lds width=16 (wave-uniform base + lane*16).  XOR swizzle:
// 16B block c of row r lives at physical block c ^ ((r>>1)&3); staging
// fetches the permuted global block, fragment reads un-permute.  This keeps
// ds_read_b128 bank aliasing at 2-way (free, m136) with zero padding.

__device__ __forceinline__ void stage_tile(const _Float16* __restrict__ g,
                                           int gstride, _Float16* lds,
                                           int w, int lane)
{
#pragma unroll
    for (int j = 0; j < 2; ++j) {
        int grp = w * 2 + j;                      // 16-row group 0..7
        int r   = grp * 16 + (lane >> 2);         // 0..127
        int cb  = (lane & 3) ^ ((r >> 1) & 3);    // logical 16B block to fetch
        const _Float16* gp = g + (size_t)r * gstride + cb * 8;
        _Float16* lp = lds + grp * 512;           // wave-uniform base
        __builtin_amdgcn_global_load_lds(
            (const __attribute__((address_space(1))) void*)gp,
            (__attribute__((address_space(3))) void*)lp, 16, 0, 0);
    }
}

__device__ __forceinline__ half8 frag(const _Float16* tile, int m, int quad)
{
    return *(const half8*)&tile[m * 32 + ((quad ^ ((m >> 1) & 3)) * 8)];
}

// ---------------------------------------------------------------------------
// Kernel 0: prep — fp16 copies of x, Wq, Wk so the projection GEMM can use
// pure global_load_lds staging (no fp32->fp16 convert in the staging path).
// ---------------------------------------------------------------------------
__global__ __launch_bounds__(256) void prep_kernel(
    const float* __restrict__ x, const float* __restrict__ Wq,
    const float* __restrict__ Wk,
    _Float16* __restrict__ xh, _Float16* __restrict__ wqh,
    _Float16* __restrict__ wkh)
{
    const int XQ = (BB * NN * DD) / 4;   // 2097152 float4s
    const int WQ = (DD * DD) / 4;        // 65536
    int t = blockIdx.x * 256 + threadIdx.x;
    const float* src; _Float16* dst; int i;
    if (t < XQ)             { src = x;  dst = xh;  i = t; }
    else if (t < XQ + WQ)   { src = Wq; dst = wqh; i = t - XQ; }
    else if (t < XQ + 2*WQ) { src = Wk; dst = wkh; i = t - XQ - WQ; }
    else return;
    float4v f = *(const float4v*)&src[(size_t)i * 4];
    half4 h;
    for (int j = 0; j < 4; ++j) h[j] = (_Float16)f[j];
    *(half4*)&dst[(size_t)i * 4] = h;
}

// ---------------------------------------------------------------------------
// Kernel 1: Q/K projection (fp16 inputs, m97 staging).
// C[m][e] = sum_d xh[m][d] * Wh[e][d]   (NT GEMM, K=512)
// ---------------------------------------------------------------------------
__global__ __launch_bounds__(256) void projqk_kernel(
    const _Float16* __restrict__ xh,
    const _Float16* __restrict__ wqh, const _Float16* __restrict__ wkh,
    const float* __restrict__ bq, const float* __restrict__ bk,
    _Float16* __restrict__ qb, _Float16* __restrict__ kb)
{
    const int z = blockIdx.z;                       // 0=q 1=k
    const _Float16* Wh  = z ? wkh : wqh;
    const float*    bias= z ? bk  : bq;
    _Float16*       outp= z ? kb  : qb;
    const int r0 = blockIdx.y * 128;
    const int c0 = blockIdx.x * 128;

    __shared__ __align__(16) _Float16 As[128 * 32];
    __shared__ __align__(16) _Float16 Bs[128 * 32];

    const int tid  = threadIdx.x;
    const int lane = tid & 63;
    const int w    = tid >> 6;
    const int wm   = w >> 1, wn = w & 1;
    const int lr   = lane & 15;
    const int quad = lane >> 4;

    floatx4 zero; zero[0]=0.f; zero[1]=0.f; zero[2]=0.f; zero[3]=0.f;
    floatx4 acc[4][4];
    for (int i = 0; i < 4; ++i)
        for (int j = 0; j < 4; ++j) acc[i][j] = zero;

    for (int kt = 0; kt < DD / 32; ++kt) {
        __syncthreads();
        stage_tile(xh + (size_t)r0 * DD + kt * 32, DD, As, w, lane);
        stage_tile(Wh + (size_t)c0 * DD + kt * 32, DD, Bs, w, lane);
        __syncthreads();
        half8 a[4], b[4];
        for (int mt = 0; mt < 4; ++mt) a[mt] = frag(As, wm * 64 + mt * 16 + lr, quad);
        for (int nt = 0; nt < 4; ++nt) b[nt] = frag(Bs, wn * 64 + nt * 16 + lr, quad);
        for (int mt = 0; mt < 4; ++mt)
            for (int nt = 0; nt < 4; ++nt)
                acc[mt][nt] = __builtin_amdgcn_mfma_f32_16x16x32_f16(a[mt], b[nt], acc[mt][nt], 0, 0, 0);
    }

    for (int mt = 0; mt < 4; ++mt)
        for (int nt = 0; nt < 4; ++nt)
            for (int r = 0; r < 4; ++r) {
                int row = r0 + wm * 64 + mt * 16 + quad * 4 + r;
                int col = c0 + wn * 64 + nt * 16 + lr;
                outp[(size_t)row * DD + col] = (_Float16)(acc[mt][nt][r] + bias[col]);
            }
}

// ---------------------------------------------------------------------------
// Kernel 1b: V projection, TRANSPOSED output (R3 form — fp32 sources need
// in-staging hi/lo conversion, so no global_load_lds here).
// Vt[b][e][n] = sum_d Wv[e][d] * x[b,n][d]; 3-product hi/lo split.
// ---------------------------------------------------------------------------
__global__ __launch_bounds__(256) void projv_kernel(
    const float* __restrict__ x,
    const float* __restrict__ Wv, const float* __restrict__ bv,
    _Float16* __restrict__ vhT, _Float16* __restrict__ vlT)
{
    const int b  = blockIdx.z;
    const int e0 = blockIdx.y * 128;
    const int n0 = blockIdx.x * 128;

    __shared__ __align__(16) _Float16 As[2][128][40];
    __shared__ __align__(16) _Float16 Bs[2][128][40];

    const int tid  = threadIdx.x;
    const int lane = tid & 63;
    const int w    = tid >> 6;
    const int wm   = w >> 1, wn = w & 1;
    const int lr   = lane & 15;
    const int quad = lane >> 4;
    const int koff = quad * 8;

    floatx4 zero; zero[0]=0.f; zero[1]=0.f; zero[2]=0.f; zero[3]=0.f;
    floatx4 acc[4][4];
    for (int i = 0; i < 4; ++i)
        for (int j = 0; j < 4; ++j) acc[i][j] = zero;

    for (int kt = 0; kt < DD / 32; ++kt) {
        __syncthreads();
        for (int i = 0; i < 4; ++i) {
            int c   = tid + i * 256;
            int row = c >> 3;
            int kc  = (c & 7) * 4;
            float4v fa = *(const float4v*)&Wv[(size_t)(e0 + row) * DD + kt * 32 + kc];
            float4v fb = *(const float4v*)&x[((size_t)b * NN + n0 + row) * DD + kt * 32 + kc];
            half4 ha, hb, la, lb;
            for (int j = 0; j < 4; ++j) {
                ha[j] = (_Float16)fa[j];  la[j] = (_Float16)(fa[j] - (float)ha[j]);
                hb[j] = (_Float16)fb[j];  lb[j] = (_Float16)(fb[j] - (float)hb[j]);
            }
            *(half4*)&As[0][row][kc] = ha;
            *(half4*)&As[1][row][kc] = la;
            *(half4*)&Bs[0][row][kc] = hb;
            *(half4*)&Bs[1][row][kc] = lb;
        }
        __syncthreads();

        half8 ah[4], al[4], bh[4], bl[4];
        for (int mt = 0; mt < 4; ++mt) {
            int m = wm * 64 + mt * 16 + lr;
            ah[mt] = *(const half8*)&As[0][m][koff];
            al[mt] = *(const half8*)&As[1][m][koff];
        }
        for (int nt = 0; nt < 4; ++nt) {
            int n = wn * 64 + nt * 16 + lr;
            bh[nt] = *(const half8*)&Bs[0][n][koff];
            bl[nt] = *(const half8*)&Bs[1][n][koff];
        }
        for (int mt = 0; mt < 4; ++mt)
            for (int nt = 0; nt < 4; ++nt) {
                acc[mt][nt] = __builtin_amdgcn_mfma_f32_16x16x32_f16(ah[mt], bh[nt], acc[mt][nt], 0, 0, 0);
                acc[mt][nt] = __builtin_amdgcn_mfma_f32_16x16x32_f16(ah[mt], bl[nt], acc[mt][nt], 0, 0, 0);
                acc[mt][nt] = __builtin_amdgcn_mfma_f32_16x16x32_f16(al[mt], bh[nt], acc[mt][nt], 0, 0, 0);
            }
    }

    for (int mt = 0; mt < 4; ++mt)
        for (int nt = 0; nt < 4; ++nt)
            for (int r = 0; r < 4; ++r) {
                int e = e0 + wm * 64 + mt * 16 + quad * 4 + r;
                int n = n0 + wn * 64 + nt * 16 + lr;
                float v = acc[mt][nt][r] + bv[e];
                size_t idx = ((size_t)b * DD + e) * NN + n;
                _Float16 h = (_Float16)v;
                vhT[idx] = h;
                vlT[idx] = (_Float16)(v - (float)h);
            }
}

// ---------------------------------------------------------------------------
// Kernel 2: S = (Q.K^T)/sqrt(512), masked -> fp16 (m97 staging).
// ---------------------------------------------------------------------------
__global__ __launch_bounds__(256) void scores_kernel(
    const _Float16* __restrict__ qb, const _Float16* __restrict__ kb,
    const int* __restrict__ lens, _Float16* __restrict__ S)
{
    const int b  = blockIdx.z;
    const int r0 = blockIdx.y * 128;
    const int c0 = blockIdx.x * 128;
    const _Float16* A  = qb + (size_t)b * NN * DD;
    const _Float16* Bm = kb + (size_t)b * NN * DD;

    __shared__ __align__(16) _Float16 As[128 * 32];
    __shared__ __align__(16) _Float16 Bs[128 * 32];

    const int tid  = threadIdx.x;
    const int lane = tid & 63;
    const int w    = tid >> 6;
    const int wm   = w >> 1, wn = w & 1;
    const int lr   = lane & 15;
    const int quad = lane >> 4;

    floatx4 zero; zero[0]=0.f; zero[1]=0.f; zero[2]=0.f; zero[3]=0.f;
    floatx4 acc[4][4];
    for (int i = 0; i < 4; ++i)
        for (int j = 0; j < 4; ++j) acc[i][j] = zero;

    for (int kt = 0; kt < DD / 32; ++kt) {
        __syncthreads();
        stage_tile(A  + (size_t)r0 * DD + kt * 32, DD, As, w, lane);
        stage_tile(Bm + (size_t)c0 * DD + kt * 32, DD, Bs, w, lane);
        __syncthreads();
        half8 a[4], bfr[4];
        for (int mt = 0; mt < 4; ++mt) a[mt]   = frag(As, wm * 64 + mt * 16 + lr, quad);
        for (int nt = 0; nt < 4; ++nt) bfr[nt] = frag(Bs, wn * 64 + nt * 16 + lr, quad);
        for (int mt = 0; mt < 4; ++mt)
            for (int nt = 0; nt < 4; ++nt)
                acc[mt][nt] = __builtin_amdgcn_mfma_f32_16x16x32_f16(a[mt], bfr[nt], acc[mt][nt], 0, 0, 0);
    }

    const int L = lens[b];
    const float scale = 0.044194173824159216f;   // 1/sqrt(512)
    const _Float16 sentinel = (_Float16)(-30000.0f);
    for (int mt = 0; mt < 4; ++mt)
        for (int nt = 0; nt < 4; ++nt)
            for (int r = 0; r < 4; ++r) {
                int q    = r0 + wm * 64 + mt * 16 + quad * 4 + r;
                int kcol = c0 + wn * 64 + nt * 16 + lr;
                float s  = acc[mt][nt][r] * scale;
                _Float16 o = (q < L && kcol < L) ? (_Float16)s : sentinel;
                S[((size_t)b * NN + q) * NN + kcol] = o;
            }
}

// ---------------------------------------------------------------------------
// Kernel 3: in-place row softmax on S (fp16), fp32 math.  One block per row.
// ---------------------------------------------------------------------------
__global__ __launch_bounds__(256) void softmax_kernel(_Float16* __restrict__ S)
{
    const size_t base = ((size_t)blockIdx.y * NN + blockIdx.x) * NN;
    const int tid  = threadIdx.x;
    const int lane = tid & 63;
    const int w    = tid >> 6;

    half8 v = *(const half8*)&S[base + tid * 8];
    float f[8];
    for (int j = 0; j < 8; ++j) f[j] = (float)v[j];

    float m = f[0];
    for (int j = 1; j < 8; ++j) m = fmaxf(m, f[j]);
    for (int off = 32; off > 0; off >>= 1) m = fmaxf(m, __shfl_xor(m, off));
    __shared__ float redm[4];
    __shared__ float reds[4];
    if (lane == 0) redm[w] = m;
    __syncthreads();
    m = fmaxf(fmaxf(redm[0], redm[1]), fmaxf(redm[2], redm[3]));

    float e[8], s = 0.f;
    for (int j = 0; j < 8; ++j) { e[j] = __expf(f[j] - m); s += e[j]; }
    for (int off = 32; off > 0; off >>= 1) s += __shfl_xor(s, off);
    if (lane == 0) reds[w] = s;
    __syncthreads();
    s = (reds[0] + reds[1]) + (reds[2] + reds[3]);

    float inv = 1.0f / s;
    half8 o;
    for (int j = 0; j < 8; ++j) o[j] = (_Float16)(e[j] * inv);
    *(half8*)&S[base + tid * 8] = o;
}

// ---------------------------------------------------------------------------
// Kernel 4: O[b][q][e] = sum_k P[b][q][k] * Vt[b][e][k], V = vhi+vlo
// (m97 staging on all three tiles).
// ---------------------------------------------------------------------------
__global__ __launch_bounds__(256) void pv_kernel(
    const _Float16* __restrict__ P, const _Float16* __restrict__ vhT,
    const _Float16* __restrict__ vlT, float* __restrict__ out)
{
    const int b  = blockIdx.z;
    const int r0 = blockIdx.y * 128;   // q rows
    const int c0 = blockIdx.x * 128;   // e cols
    const _Float16* A  = P   + (size_t)b * NN * NN;
    const _Float16* Vh = vhT + (size_t)b * DD * NN;
    const _Float16* Vl = vlT + (size_t)b * DD * NN;

    __shared__ __align__(16) _Float16 As[128 * 32];
    __shared__ __align__(16) _Float16 Bhs[128 * 32];
    __shared__ __align__(16) _Float16 Bls[128 * 32];

    const int tid  = threadIdx.x;
    const int lane = tid & 63;
    const int w    = tid >> 6;
    const int wm   = w >> 1, wn = w & 1;
    const int lr   = lane & 15;
    const int quad = lane >> 4;

    floatx4 zero; zero[0]=0.f; zero[1]=0.f; zero[2]=0.f; zero[3]=0.f;
    floatx4 acc[4][4];
    for (int i = 0; i < 4; ++i)
        for (int j = 0; j < 4; ++j) acc[i][j] = zero;

    for (int kt = 0; kt < NN / 32; ++kt) {
        __syncthreads();
        stage_tile(A  + (size_t)r0 * NN + kt * 32, NN, As,  w, lane);
        stage_tile(Vh + (size_t)c0 * NN + kt * 32, NN, Bhs, w, lane);
        stage_tile(Vl + (size_t)c0 * NN + kt * 32, NN, Bls, w, lane);
        __syncthreads();

        half8 a[4], bh[4], bl[4];
        for (int mt = 0; mt < 4; ++mt) a[mt]  = frag(As,  wm * 64 + mt * 16 + lr, quad);
        for (int nt = 0; nt < 4; ++nt) {
            bh[nt] = frag(Bhs, wn * 64 + nt * 16 + lr, quad);
            bl[nt] = frag(Bls, wn * 64 + nt * 16 + lr, quad);
        }
        for (int mt = 0; mt < 4; ++mt)
            for (int nt = 0; nt < 4; ++nt) {
                acc[mt][nt] = __builtin_amdgcn_mfma_f32_16x16x32_f16(a[mt], bh[nt], acc[mt][nt], 0, 0, 0);
                acc[mt][nt] = __builtin_amdgcn_mfma_f32_16x16x32_f16(a[mt], bl[nt], acc[mt][nt], 0, 0, 0);
            }
    }

    for (int mt = 0; mt < 4; ++mt)
        for (int nt = 0; nt < 4; ++nt)
            for (int r = 0; r < 4; ++r) {
                int q = r0 + wm * 64 + mt * 16 + quad * 4 + r;
                int e = c0 + wn * 64 + nt * 16 + lr;
                out[((size_t)b * NN + q) * DD + e] = acc[mt][nt][r];
            }
}

// ---------------------------------------------------------------------------
extern "C" void kernel_launch(void* const* d_in, const int* in_sizes, int n_in,
                              void* d_out, int out_size, void* d_ws, size_t ws_size,
                              hipStream_t stream) {
    const float* x    = (const float*)d_in[0];
    const int*   lens = (const int*)d_in[1];   // harness delivers integer inputs as int32
    const float* Wq   = (const float*)d_in[2];
    const float* bq   = (const float*)d_in[3];
    const float* Wk   = (const float*)d_in[4];
    const float* bk   = (const float*)d_in[5];
    const float* Wv   = (const float*)d_in[6];
    const float* bv   = (const float*)d_in[7];
    float* out = (float*)d_out;

    // workspace layout (128 MiB):
    //   0:    qb (16M)
    //   16M:  kb (16M)
    //   32M:  vhT (16M)
    //   48M:  vlT (16M)
    //   64M:  S (64M) — first 17M overlaid by [xh 16M | wqh .5M | wkh .5M],
    //         dead before scores_kernel writes S (stream-ordered).
    char* ws = (char*)d_ws;
    const size_t MB = 1024 * 1024;
    _Float16* qb  = (_Float16*)(ws);
    _Float16* kb  = (_Float16*)(ws + 16 * MB);
    _Float16* vh  = (_Float16*)(ws + 32 * MB);
    _Float16* vl  = (_Float16*)(ws + 48 * MB);
    _Float16* S   = (_Float16*)(ws + 64 * MB);
    _Float16* xh  = (_Float16*)(ws + 64 * MB);
    _Float16* wqh = (_Float16*)(ws + 80 * MB);
    _Float16* wkh = (_Float16*)(ws + 80 * MB + 512 * 1024);

    prep_kernel  <<<8704, 256, 0, stream>>>(x, Wq, Wk, xh, wqh, wkh);
    projqk_kernel<<<dim3(4, 128, 2), 256, 0, stream>>>(xh, wqh, wkh, bq, bk, qb, kb);
    projv_kernel <<<dim3(16, 4, 8),  256, 0, stream>>>(x, Wv, bv, vh, vl);
    scores_kernel<<<dim3(16, 16, 8), 256, 0, stream>>>(qb, kb, lens, S);
    softmax_kernel<<<dim3(2048, 8, 1), 256, 0, stream>>>(S);
    pv_kernel    <<<dim3(4, 16, 8),  256, 0, stream>>>(S, vh, vl, out);
}

// Round 5
// 269.893 us; speedup vs baseline: 2.1116x; 1.1704x over previous
//
#include <hip/hip_runtime.h>

typedef _Float16 half8 __attribute__((ext_vector_type(8)));
typedef _Float16 half4 __attribute__((ext_vector_type(4)));
typedef float    floatx4 __attribute__((ext_vector_type(4)));
typedef float    float4v __attribute__((ext_vector_type(4)));

#define BB 8
#define NN 2048
#define DD 512

// MFMA fragment mapping (gfx950, 16x16x32, m89/m91/m120-verified):
//   A-operand: A[m = lane&15][k = (lane>>4)*8 + j], j=0..7 contiguous
//   B-operand: B[n = lane&15][k = (lane>>4)*8 + j]   (NT: both contiguous in k)
//   C/D:       col = lane&15, row = (lane>>4)*4 + reg
//
// m97-style staging: unpadded [128][32] fp16 LDS tiles filled by
// global_load_lds width=16 (wave-uniform base + lane*16).  XOR swizzle:
// 16B block c of row r lives at physical block c ^ ((r>>1)&3); staging
// fetches the permuted global block, fragment reads un-permute.  Keeps
// ds_read_b128 bank aliasing at 2-way (free, m136) with zero padding.
// R4 measured: SQ_LDS_BANK_CONFLICT == 0 with this scheme.

__device__ __forceinline__ void stage_tile(const _Float16* __restrict__ g,
                                           int gstride, _Float16* lds,
                                           int w, int lane)
{
#pragma unroll
    for (int j = 0; j < 2; ++j) {
        int grp = w * 2 + j;                      // 16-row group 0..7
        int r   = grp * 16 + (lane >> 2);         // 0..127
        int cb  = (lane & 3) ^ ((r >> 1) & 3);    // logical 16B block to fetch
        const _Float16* gp = g + (size_t)r * gstride + cb * 8;
        _Float16* lp = lds + grp * 512;           // wave-uniform base
        __builtin_amdgcn_global_load_lds(
            (const __attribute__((address_space(1))) void*)gp,
            (__attribute__((address_space(3))) void*)lp, 16, 0, 0);
    }
}

__device__ __forceinline__ half8 frag(const _Float16* tile, int m, int quad)
{
    return *(const half8*)&tile[m * 32 + ((quad ^ ((m >> 1) & 3)) * 8)];
}

// ---------------------------------------------------------------------------
// Kernel 0: prep — fp16 copies of x, Wq, Wk, Wv so all projection GEMMs use
// pure global_load_lds staging (no fp32->fp16 convert in the staging path).
// ---------------------------------------------------------------------------
__global__ __launch_bounds__(256) void prep_kernel(
    const float* __restrict__ x, const float* __restrict__ Wq,
    const float* __restrict__ Wk, const float* __restrict__ Wv,
    _Float16* __restrict__ xh, _Float16* __restrict__ wqh,
    _Float16* __restrict__ wkh, _Float16* __restrict__ wvh)
{
    const int XQ = (BB * NN * DD) / 4;   // 2097152 float4s
    const int WQ = (DD * DD) / 4;        // 65536
    int t = blockIdx.x * 256 + threadIdx.x;
    const float* src; _Float16* dst; int i;
    if (t < XQ)             { src = x;  dst = xh;  i = t; }
    else if (t < XQ + WQ)   { src = Wq; dst = wqh; i = t - XQ; }
    else if (t < XQ + 2*WQ) { src = Wk; dst = wkh; i = t - XQ - 2*WQ + WQ; }
    else if (t < XQ + 3*WQ) { src = Wv; dst = wvh; i = t - XQ - 2*WQ; }
    else return;
    float4v f = *(const float4v*)&src[(size_t)i * 4];
    half4 h;
    for (int j = 0; j < 4; ++j) h[j] = (_Float16)f[j];
    *(half4*)&dst[(size_t)i * 4] = h;
}

// ---------------------------------------------------------------------------
// Kernel 1: Q/K projection (fp16 inputs, m97 staging).
// C[m][e] = sum_d xh[m][d] * Wh[e][d]   (NT GEMM, K=512)
// ---------------------------------------------------------------------------
__global__ __launch_bounds__(256) void projqk_kernel(
    const _Float16* __restrict__ xh,
    const _Float16* __restrict__ wqh, const _Float16* __restrict__ wkh,
    const float* __restrict__ bq, const float* __restrict__ bk,
    _Float16* __restrict__ qb, _Float16* __restrict__ kb)
{
    const int z = blockIdx.z;                       // 0=q 1=k
    const _Float16* Wh  = z ? wkh : wqh;
    const float*    bias= z ? bk  : bq;
    _Float16*       outp= z ? kb  : qb;
    const int r0 = blockIdx.y * 128;
    const int c0 = blockIdx.x * 128;

    __shared__ __align__(16) _Float16 As[128 * 32];
    __shared__ __align__(16) _Float16 Bs[128 * 32];

    const int tid  = threadIdx.x;
    const int lane = tid & 63;
    const int w    = tid >> 6;
    const int wm   = w >> 1, wn = w & 1;
    const int lr   = lane & 15;
    const int quad = lane >> 4;

    floatx4 zero; zero[0]=0.f; zero[1]=0.f; zero[2]=0.f; zero[3]=0.f;
    floatx4 acc[4][4];
    for (int i = 0; i < 4; ++i)
        for (int j = 0; j < 4; ++j) acc[i][j] = zero;

    for (int kt = 0; kt < DD / 32; ++kt) {
        __syncthreads();
        stage_tile(xh + (size_t)r0 * DD + kt * 32, DD, As, w, lane);
        stage_tile(Wh + (size_t)c0 * DD + kt * 32, DD, Bs, w, lane);
        __syncthreads();
        half8 a[4], b[4];
        for (int mt = 0; mt < 4; ++mt) a[mt] = frag(As, wm * 64 + mt * 16 + lr, quad);
        for (int nt = 0; nt < 4; ++nt) b[nt] = frag(Bs, wn * 64 + nt * 16 + lr, quad);
        for (int mt = 0; mt < 4; ++mt)
            for (int nt = 0; nt < 4; ++nt)
                acc[mt][nt] = __builtin_amdgcn_mfma_f32_16x16x32_f16(a[mt], b[nt], acc[mt][nt], 0, 0, 0);
    }

    for (int mt = 0; mt < 4; ++mt)
        for (int nt = 0; nt < 4; ++nt)
            for (int r = 0; r < 4; ++r) {
                int row = r0 + wm * 64 + mt * 16 + quad * 4 + r;
                int col = c0 + wn * 64 + nt * 16 + lr;
                outp[(size_t)row * DD + col] = (_Float16)(acc[mt][nt][r] + bias[col]);
            }
}

// ---------------------------------------------------------------------------
// Kernel 1b: V projection, TRANSPOSED output, plain fp16, m97 staging.
// Vt[b][e][n] = sum_d wvh[e][d] * xh[b,n][d]  (A = Wv rows, B = x rows; C/D
// col dim (lane&15) is contiguous n -> coalesced-enough stores, and pv can
// stage V^T with conflict-free global_load_lds).
// ---------------------------------------------------------------------------
__global__ __launch_bounds__(256) void projv_kernel(
    const _Float16* __restrict__ xh,
    const _Float16* __restrict__ wvh, const float* __restrict__ bv,
    _Float16* __restrict__ vhT)
{
    const int b  = blockIdx.z;
    const int e0 = blockIdx.y * 128;   // 4 tiles over D=512 (rows of Vt)
    const int n0 = blockIdx.x * 128;   // 16 tiles over N=2048 (cols of Vt)

    __shared__ __align__(16) _Float16 As[128 * 32];
    __shared__ __align__(16) _Float16 Bs[128 * 32];

    const int tid  = threadIdx.x;
    const int lane = tid & 63;
    const int w    = tid >> 6;
    const int wm   = w >> 1, wn = w & 1;
    const int lr   = lane & 15;
    const int quad = lane >> 4;

    floatx4 zero; zero[0]=0.f; zero[1]=0.f; zero[2]=0.f; zero[3]=0.f;
    floatx4 acc[4][4];
    for (int i = 0; i < 4; ++i)
        for (int j = 0; j < 4; ++j) acc[i][j] = zero;

    for (int kt = 0; kt < DD / 32; ++kt) {
        __syncthreads();
        stage_tile(wvh + (size_t)e0 * DD + kt * 32, DD, As, w, lane);
        stage_tile(xh + ((size_t)b * NN + n0) * DD + kt * 32, DD, Bs, w, lane);
        __syncthreads();
        half8 a[4], bfr[4];
        for (int mt = 0; mt < 4; ++mt) a[mt]   = frag(As, wm * 64 + mt * 16 + lr, quad);
        for (int nt = 0; nt < 4; ++nt) bfr[nt] = frag(Bs, wn * 64 + nt * 16 + lr, quad);
        for (int mt = 0; mt < 4; ++mt)
            for (int nt = 0; nt < 4; ++nt)
                acc[mt][nt] = __builtin_amdgcn_mfma_f32_16x16x32_f16(a[mt], bfr[nt], acc[mt][nt], 0, 0, 0);
    }

    for (int mt = 0; mt < 4; ++mt)
        for (int nt = 0; nt < 4; ++nt)
            for (int r = 0; r < 4; ++r) {
                int e = e0 + wm * 64 + mt * 16 + quad * 4 + r;   // row of Vt
                int n = n0 + wn * 64 + nt * 16 + lr;             // col of Vt
                vhT[((size_t)b * DD + e) * NN + n] = (_Float16)(acc[mt][nt][r] + bv[e]);
            }
}

// ---------------------------------------------------------------------------
// Kernel 2: S = (Q.K^T)/sqrt(512), masked -> fp16 (m97 staging).
// Mask: valid iff (q<L && k<L), else sentinel -30000 (identical fp16 value
// everywhere -> uniform softmax for rows q>=L) — matches ref semantics.
// ---------------------------------------------------------------------------
__global__ __launch_bounds__(256) void scores_kernel(
    const _Float16* __restrict__ qb, const _Float16* __restrict__ kb,
    const int* __restrict__ lens, _Float16* __restrict__ S)
{
    const int b  = blockIdx.z;
    const int r0 = blockIdx.y * 128;
    const int c0 = blockIdx.x * 128;
    const _Float16* A  = qb + (size_t)b * NN * DD;
    const _Float16* Bm = kb + (size_t)b * NN * DD;

    __shared__ __align__(16) _Float16 As[128 * 32];
    __shared__ __align__(16) _Float16 Bs[128 * 32];

    const int tid  = threadIdx.x;
    const int lane = tid & 63;
    const int w    = tid >> 6;
    const int wm   = w >> 1, wn = w & 1;
    const int lr   = lane & 15;
    const int quad = lane >> 4;

    floatx4 zero; zero[0]=0.f; zero[1]=0.f; zero[2]=0.f; zero[3]=0.f;
    floatx4 acc[4][4];
    for (int i = 0; i < 4; ++i)
        for (int j = 0; j < 4; ++j) acc[i][j] = zero;

    for (int kt = 0; kt < DD / 32; ++kt) {
        __syncthreads();
        stage_tile(A  + (size_t)r0 * DD + kt * 32, DD, As, w, lane);
        stage_tile(Bm + (size_t)c0 * DD + kt * 32, DD, Bs, w, lane);
        __syncthreads();
        half8 a[4], bfr[4];
        for (int mt = 0; mt < 4; ++mt) a[mt]   = frag(As, wm * 64 + mt * 16 + lr, quad);
        for (int nt = 0; nt < 4; ++nt) bfr[nt] = frag(Bs, wn * 64 + nt * 16 + lr, quad);
        for (int mt = 0; mt < 4; ++mt)
            for (int nt = 0; nt < 4; ++nt)
                acc[mt][nt] = __builtin_amdgcn_mfma_f32_16x16x32_f16(a[mt], bfr[nt], acc[mt][nt], 0, 0, 0);
    }

    const int L = lens[b];
    const float scale = 0.044194173824159216f;   // 1/sqrt(512)
    const _Float16 sentinel = (_Float16)(-30000.0f);
    for (int mt = 0; mt < 4; ++mt)
        for (int nt = 0; nt < 4; ++nt)
            for (int r = 0; r < 4; ++r) {
                int q    = r0 + wm * 64 + mt * 16 + quad * 4 + r;
                int kcol = c0 + wn * 64 + nt * 16 + lr;
                float s  = acc[mt][nt][r] * scale;
                _Float16 o = (q < L && kcol < L) ? (_Float16)s : sentinel;
                S[((size_t)b * NN + q) * NN + kcol] = o;
            }
}

// ---------------------------------------------------------------------------
// Kernel 3: in-place row softmax on S (fp16), fp32 math.  One block per row.
// ---------------------------------------------------------------------------
__global__ __launch_bounds__(256) void softmax_kernel(_Float16* __restrict__ S)
{
    const size_t base = ((size_t)blockIdx.y * NN + blockIdx.x) * NN;
    const int tid  = threadIdx.x;
    const int lane = tid & 63;
    const int w    = tid >> 6;

    half8 v = *(const half8*)&S[base + tid * 8];
    float f[8];
    for (int j = 0; j < 8; ++j) f[j] = (float)v[j];

    float m = f[0];
    for (int j = 1; j < 8; ++j) m = fmaxf(m, f[j]);
    for (int off = 32; off > 0; off >>= 1) m = fmaxf(m, __shfl_xor(m, off));
    __shared__ float redm[4];
    __shared__ float reds[4];
    if (lane == 0) redm[w] = m;
    __syncthreads();
    m = fmaxf(fmaxf(redm[0], redm[1]), fmaxf(redm[2], redm[3]));

    float e[8], s = 0.f;
    for (int j = 0; j < 8; ++j) { e[j] = __expf(f[j] - m); s += e[j]; }
    for (int off = 32; off > 0; off >>= 1) s += __shfl_xor(s, off);
    if (lane == 0) reds[w] = s;
    __syncthreads();
    s = (reds[0] + reds[1]) + (reds[2] + reds[3]);

    float inv = 1.0f / s;
    half8 o;
    for (int j = 0; j < 8; ++j) o[j] = (_Float16)(e[j] * inv);
    *(half8*)&S[base + tid * 8] = o;
}

// ---------------------------------------------------------------------------
// Kernel 4: O[b][q][e] = sum_k P[b][q][k] * Vt[b][e][k]  (m97 staging, plain
// fp16 V — lo-term bounded by max|vlo| <= ~1e-3, inside the error budget).
// ---------------------------------------------------------------------------
__global__ __launch_bounds__(256) void pv_kernel(
    const _Float16* __restrict__ P, const _Float16* __restrict__ vhT,
    float* __restrict__ out)
{
    const int b  = blockIdx.z;
    const int r0 = blockIdx.y * 128;   // q rows
    const int c0 = blockIdx.x * 128;   // e cols
    const _Float16* A  = P   + (size_t)b * NN * NN;
    const _Float16* Vh = vhT + (size_t)b * DD * NN;

    __shared__ __align__(16) _Float16 As[128 * 32];
    __shared__ __align__(16) _Float16 Bhs[128 * 32];

    const int tid  = threadIdx.x;
    const int lane = tid & 63;
    const int w    = tid >> 6;
    const int wm   = w >> 1, wn = w & 1;
    const int lr   = lane & 15;
    const int quad = lane >> 4;

    floatx4 zero; zero[0]=0.f; zero[1]=0.f; zero[2]=0.f; zero[3]=0.f;
    floatx4 acc[4][4];
    for (int i = 0; i < 4; ++i)
        for (int j = 0; j < 4; ++j) acc[i][j] = zero;

    for (int kt = 0; kt < NN / 32; ++kt) {
        __syncthreads();
        stage_tile(A  + (size_t)r0 * NN + kt * 32, NN, As,  w, lane);
        stage_tile(Vh + (size_t)c0 * NN + kt * 32, NN, Bhs, w, lane);
        __syncthreads();

        half8 a[4], bh[4];
        for (int mt = 0; mt < 4; ++mt) a[mt]  = frag(As,  wm * 64 + mt * 16 + lr, quad);
        for (int nt = 0; nt < 4; ++nt) bh[nt] = frag(Bhs, wn * 64 + nt * 16 + lr, quad);
        for (int mt = 0; mt < 4; ++mt)
            for (int nt = 0; nt < 4; ++nt)
                acc[mt][nt] = __builtin_amdgcn_mfma_f32_16x16x32_f16(a[mt], bh[nt], acc[mt][nt], 0, 0, 0);
    }

    for (int mt = 0; mt < 4; ++mt)
        for (int nt = 0; nt < 4; ++nt)
            for (int r = 0; r < 4; ++r) {
                int q = r0 + wm * 64 + mt * 16 + quad * 4 + r;
                int e = c0 + wn * 64 + nt * 16 + lr;
                out[((size_t)b * NN + q) * DD + e] = acc[mt][nt][r];
            }
}

// ---------------------------------------------------------------------------
extern "C" void kernel_launch(void* const* d_in, const int* in_sizes, int n_in,
                              void* d_out, int out_size, void* d_ws, size_t ws_size,
                              hipStream_t stream) {
    const float* x    = (const float*)d_in[0];
    const int*   lens = (const int*)d_in[1];   // harness delivers integer inputs as int32
    const float* Wq   = (const float*)d_in[2];
    const float* bq   = (const float*)d_in[3];
    const float* Wk   = (const float*)d_in[4];
    const float* bk   = (const float*)d_in[5];
    const float* Wv   = (const float*)d_in[6];
    const float* bv   = (const float*)d_in[7];
    float* out = (float*)d_out;

    // workspace layout (128 MiB):
    //   0:    qb (16M)
    //   16M:  kb (16M)
    //   32M:  vhT (16M)
    //   48M:  (free)
    //   64M:  S (64M) — first ~18M overlaid by [xh 16M | wqh | wkh | wvh],
    //         dead before scores_kernel writes S (stream-ordered).
    char* ws = (char*)d_ws;
    const size_t MB = 1024 * 1024;
    _Float16* qb  = (_Float16*)(ws);
    _Float16* kb  = (_Float16*)(ws + 16 * MB);
    _Float16* vh  = (_Float16*)(ws + 32 * MB);
    _Float16* S   = (_Float16*)(ws + 64 * MB);
    _Float16* xh  = (_Float16*)(ws + 64 * MB);
    _Float16* wqh = (_Float16*)(ws + 80 * MB);
    _Float16* wkh = (_Float16*)(ws + 80 * MB + 512 * 1024);
    _Float16* wvh = (_Float16*)(ws + 81 * MB);

    prep_kernel  <<<8960, 256, 0, stream>>>(x, Wq, Wk, Wv, xh, wqh, wkh, wvh);
    projqk_kernel<<<dim3(4, 128, 2), 256, 0, stream>>>(xh, wqh, wkh, bq, bk, qb, kb);
    projv_kernel <<<dim3(16, 4, 8),  256, 0, stream>>>(xh, wvh, bv, vh);
    scores_kernel<<<dim3(16, 16, 8), 256, 0, stream>>>(qb, kb, lens, S);
    softmax_kernel<<<dim3(2048, 8, 1), 256, 0, stream>>>(S);
    pv_kernel    <<<dim3(4, 16, 8),  256, 0, stream>>>(S, vh, out);
}

// Round 6
// 221.099 us; speedup vs baseline: 2.5775x; 1.2207x over previous
//
#include <hip/hip_runtime.h>

typedef _Float16 half8 __attribute__((ext_vector_type(8)));
typedef _Float16 half4 __attribute__((ext_vector_type(4)));
typedef float    floatx4 __attribute__((ext_vector_type(4)));
typedef float    float4v __attribute__((ext_vector_type(4)));

#define BB 8
#define NN 2048
#define DD 512

// MFMA fragment mapping (gfx950, 16x16x32, m89/m91/m120-verified):
//   A-operand: A[m = lane&15][k = (lane>>4)*8 + j], j=0..7 contiguous
//   B-operand: B[n = lane&15][k = (lane>>4)*8 + j]   (NT: both contiguous in k)
//   C/D:       col = lane&15, row = (lane>>4)*4 + reg
//
// m97-style staging: unpadded [128][32] fp16 LDS tiles filled by
// global_load_lds width=16.  XOR swizzle: 16B block c of row r lives at
// physical block c ^ ((r>>1)&3).  R4/R5 measured: SQ_LDS_BANK_CONFLICT == 0.
//
// Length-aware sparsity (R6): only the (q<L)x(k<L) region is computed.
// Rows q>=L get mean(v) exactly (uniform softmax over equal sentinels).
// All grids launched full-size; blocks early-exit on device-read lens[b].

__device__ __forceinline__ void stage_tile(const _Float16* __restrict__ g,
                                           int gstride, _Float16* lds,
                                           int w, int lane)
{
#pragma unroll
    for (int j = 0; j < 2; ++j) {
        int grp = w * 2 + j;                      // 16-row group 0..7
        int r   = grp * 16 + (lane >> 2);         // 0..127
        int cb  = (lane & 3) ^ ((r >> 1) & 3);    // logical 16B block to fetch
        const _Float16* gp = g + (size_t)r * gstride + cb * 8;
        _Float16* lp = lds + grp * 512;           // wave-uniform base
        __builtin_amdgcn_global_load_lds(
            (const __attribute__((address_space(1))) void*)gp,
            (__attribute__((address_space(3))) void*)lp, 16, 0, 0);
    }
}

__device__ __forceinline__ half8 frag(const _Float16* tile, int m, int quad)
{
    return *(const half8*)&tile[m * 32 + ((quad ^ ((m >> 1) & 3)) * 8)];
}

// ---------------------------------------------------------------------------
// Kernel 0: prep — fp16 copies of x, Wq, Wk, Wv.
// ---------------------------------------------------------------------------
__global__ __launch_bounds__(256) void prep_kernel(
    const float* __restrict__ x, const float* __restrict__ Wq,
    const float* __restrict__ Wk, const float* __restrict__ Wv,
    _Float16* __restrict__ xh, _Float16* __restrict__ wqh,
    _Float16* __restrict__ wkh, _Float16* __restrict__ wvh)
{
    const int XQ = (BB * NN * DD) / 4;   // 2097152 float4s
    const int WQ = (DD * DD) / 4;        // 65536
    int t = blockIdx.x * 256 + threadIdx.x;
    const float* src; _Float16* dst; int i;
    if (t < XQ)             { src = x;  dst = xh;  i = t; }
    else if (t < XQ + WQ)   { src = Wq; dst = wqh; i = t - XQ; }
    else if (t < XQ + 2*WQ) { src = Wk; dst = wkh; i = t - XQ - WQ; }
    else if (t < XQ + 3*WQ) { src = Wv; dst = wvh; i = t - XQ - 2*WQ; }
    else return;
    float4v f = *(const float4v*)&src[(size_t)i * 4];
    half4 h;
    for (int j = 0; j < 4; ++j) h[j] = (_Float16)f[j];
    *(half4*)&dst[(size_t)i * 4] = h;
}

// ---------------------------------------------------------------------------
// Kernel 1: Q/K projection (fp16 inputs, m97 staging).  Blocks whose row
// tile (within its batch) starts >= L are never read downstream -> exit.
// ---------------------------------------------------------------------------
__global__ __launch_bounds__(256) void projqk_kernel(
    const _Float16* __restrict__ xh,
    const _Float16* __restrict__ wqh, const _Float16* __restrict__ wkh,
    const float* __restrict__ bq, const float* __restrict__ bk,
    const int* __restrict__ lens,
    _Float16* __restrict__ qb, _Float16* __restrict__ kb)
{
    const int z = blockIdx.z;                       // 0=q 1=k
    const int r0 = blockIdx.y * 128;                // global row in [0,16384)
    const int bb = r0 >> 11;                        // batch
    if ((r0 & 2047) >= lens[bb]) return;            // rows never read
    const _Float16* Wh  = z ? wkh : wqh;
    const float*    bias= z ? bk  : bq;
    _Float16*       outp= z ? kb  : qb;
    const int c0 = blockIdx.x * 128;

    __shared__ __align__(16) _Float16 As[128 * 32];
    __shared__ __align__(16) _Float16 Bs[128 * 32];

    const int tid  = threadIdx.x;
    const int lane = tid & 63;
    const int w    = tid >> 6;
    const int wm   = w >> 1, wn = w & 1;
    const int lr   = lane & 15;
    const int quad = lane >> 4;

    floatx4 zero; zero[0]=0.f; zero[1]=0.f; zero[2]=0.f; zero[3]=0.f;
    floatx4 acc[4][4];
    for (int i = 0; i < 4; ++i)
        for (int j = 0; j < 4; ++j) acc[i][j] = zero;

    for (int kt = 0; kt < DD / 32; ++kt) {
        __syncthreads();
        stage_tile(xh + (size_t)r0 * DD + kt * 32, DD, As, w, lane);
        stage_tile(Wh + (size_t)c0 * DD + kt * 32, DD, Bs, w, lane);
        __syncthreads();
        half8 a[4], b[4];
        for (int mt = 0; mt < 4; ++mt) a[mt] = frag(As, wm * 64 + mt * 16 + lr, quad);
        for (int nt = 0; nt < 4; ++nt) b[nt] = frag(Bs, wn * 64 + nt * 16 + lr, quad);
        for (int mt = 0; mt < 4; ++mt)
            for (int nt = 0; nt < 4; ++nt)
                acc[mt][nt] = __builtin_amdgcn_mfma_f32_16x16x32_f16(a[mt], b[nt], acc[mt][nt], 0, 0, 0);
    }

    for (int mt = 0; mt < 4; ++mt)
        for (int nt = 0; nt < 4; ++nt)
            for (int r = 0; r < 4; ++r) {
                int row = r0 + wm * 64 + mt * 16 + quad * 4 + r;
                int col = c0 + wn * 64 + nt * 16 + lr;
                outp[(size_t)row * DD + col] = (_Float16)(acc[mt][nt][r] + bias[col]);
            }
}

// ---------------------------------------------------------------------------
// Kernel 1b: V projection, TRANSPOSED output (all rows needed: mean_v spans
// all n).  Vt[b][e][n] = sum_d wvh[e][d] * xh[b,n][d].
// ---------------------------------------------------------------------------
__global__ __launch_bounds__(256) void projv_kernel(
    const _Float16* __restrict__ xh,
    const _Float16* __restrict__ wvh, const float* __restrict__ bv,
    _Float16* __restrict__ vhT)
{
    const int b  = blockIdx.z;
    const int e0 = blockIdx.y * 128;
    const int n0 = blockIdx.x * 128;

    __shared__ __align__(16) _Float16 As[128 * 32];
    __shared__ __align__(16) _Float16 Bs[128 * 32];

    const int tid  = threadIdx.x;
    const int lane = tid & 63;
    const int w    = tid >> 6;
    const int wm   = w >> 1, wn = w & 1;
    const int lr   = lane & 15;
    const int quad = lane >> 4;

    floatx4 zero; zero[0]=0.f; zero[1]=0.f; zero[2]=0.f; zero[3]=0.f;
    floatx4 acc[4][4];
    for (int i = 0; i < 4; ++i)
        for (int j = 0; j < 4; ++j) acc[i][j] = zero;

    for (int kt = 0; kt < DD / 32; ++kt) {
        __syncthreads();
        stage_tile(wvh + (size_t)e0 * DD + kt * 32, DD, As, w, lane);
        stage_tile(xh + ((size_t)b * NN + n0) * DD + kt * 32, DD, Bs, w, lane);
        __syncthreads();
        half8 a[4], bfr[4];
        for (int mt = 0; mt < 4; ++mt) a[mt]   = frag(As, wm * 64 + mt * 16 + lr, quad);
        for (int nt = 0; nt < 4; ++nt) bfr[nt] = frag(Bs, wn * 64 + nt * 16 + lr, quad);
        for (int mt = 0; mt < 4; ++mt)
            for (int nt = 0; nt < 4; ++nt)
                acc[mt][nt] = __builtin_amdgcn_mfma_f32_16x16x32_f16(a[mt], bfr[nt], acc[mt][nt], 0, 0, 0);
    }

    for (int mt = 0; mt < 4; ++mt)
        for (int nt = 0; nt < 4; ++nt)
            for (int r = 0; r < 4; ++r) {
                int e = e0 + wm * 64 + mt * 16 + quad * 4 + r;
                int n = n0 + wn * 64 + nt * 16 + lr;
                vhT[((size_t)b * DD + e) * NN + n] = (_Float16)(acc[mt][nt][r] + bv[e]);
            }
}

// ---------------------------------------------------------------------------
// Kernel 1c: mean_v[b][e] = (1/2048) sum_n Vt[b][e][n]  (one block per row).
// Exact value of the reference's masked-query rows (uniform softmax).
// ---------------------------------------------------------------------------
__global__ __launch_bounds__(256) void meanv_kernel(
    const _Float16* __restrict__ vhT, float* __restrict__ mean_v)
{
    const int b = blockIdx.y, e = blockIdx.x;
    const _Float16* row = vhT + ((size_t)b * DD + e) * NN;
    const int tid  = threadIdx.x;
    const int lane = tid & 63;
    const int w    = tid >> 6;

    half8 v = *(const half8*)&row[tid * 8];
    float s = 0.f;
    for (int j = 0; j < 8; ++j) s += (float)v[j];
    for (int off = 32; off > 0; off >>= 1) s += __shfl_xor(s, off);
    __shared__ float red[4];
    if (lane == 0) red[w] = s;
    __syncthreads();
    if (tid == 0)
        mean_v[b * DD + e] = (red[0] + red[1] + red[2] + red[3]) * (1.0f / 2048.0f);
}

// ---------------------------------------------------------------------------
// Kernel 2: S = (Q.K^T)/sqrt(512) -> fp16, only tiles with r0<L && c0<L.
// No masking in epilogue: softmax predicates on L, rows q>=L are overwritten
// by fill_kernel.
// ---------------------------------------------------------------------------
__global__ __launch_bounds__(256) void scores_kernel(
    const _Float16* __restrict__ qb, const _Float16* __restrict__ kb,
    const int* __restrict__ lens, _Float16* __restrict__ S)
{
    const int b  = blockIdx.z;
    const int r0 = blockIdx.y * 128;
    const int c0 = blockIdx.x * 128;
    const int L  = lens[b];
    if (r0 >= L || c0 >= L) return;
    const _Float16* A  = qb + (size_t)b * NN * DD;
    const _Float16* Bm = kb + (size_t)b * NN * DD;

    __shared__ __align__(16) _Float16 As[128 * 32];
    __shared__ __align__(16) _Float16 Bs[128 * 32];

    const int tid  = threadIdx.x;
    const int lane = tid & 63;
    const int w    = tid >> 6;
    const int wm   = w >> 1, wn = w & 1;
    const int lr   = lane & 15;
    const int quad = lane >> 4;

    floatx4 zero; zero[0]=0.f; zero[1]=0.f; zero[2]=0.f; zero[3]=0.f;
    floatx4 acc[4][4];
    for (int i = 0; i < 4; ++i)
        for (int j = 0; j < 4; ++j) acc[i][j] = zero;

    for (int kt = 0; kt < DD / 32; ++kt) {
        __syncthreads();
        stage_tile(A  + (size_t)r0 * DD + kt * 32, DD, As, w, lane);
        stage_tile(Bm + (size_t)c0 * DD + kt * 32, DD, Bs, w, lane);
        __syncthreads();
        half8 a[4], bfr[4];
        for (int mt = 0; mt < 4; ++mt) a[mt]   = frag(As, wm * 64 + mt * 16 + lr, quad);
        for (int nt = 0; nt < 4; ++nt) bfr[nt] = frag(Bs, wn * 64 + nt * 16 + lr, quad);
        for (int mt = 0; mt < 4; ++mt)
            for (int nt = 0; nt < 4; ++nt)
                acc[mt][nt] = __builtin_amdgcn_mfma_f32_16x16x32_f16(a[mt], bfr[nt], acc[mt][nt], 0, 0, 0);
    }

    const float scale = 0.044194173824159216f;   // 1/sqrt(512)
    for (int mt = 0; mt < 4; ++mt)
        for (int nt = 0; nt < 4; ++nt)
            for (int r = 0; r < 4; ++r) {
                int q    = r0 + wm * 64 + mt * 16 + quad * 4 + r;
                int kcol = c0 + wn * 64 + nt * 16 + lr;
                S[((size_t)b * NN + q) * NN + kcol] = (_Float16)(acc[mt][nt][r] * scale);
            }
}

// ---------------------------------------------------------------------------
// Kernel 3: in-place row softmax, rows q<L only, keys k<L only (per-element
// predication); writes P=0 for k in [L, ceil32(L)) so pv's last K-chunk is
// clean.  One block per row.
// ---------------------------------------------------------------------------
__global__ __launch_bounds__(256) void softmax_kernel(
    _Float16* __restrict__ S, const int* __restrict__ lens)
{
    const int b = blockIdx.y, q = blockIdx.x;
    const int L = lens[b];
    if (q >= L) return;
    const int Lp32 = (L + 31) & ~31;
    const size_t base = ((size_t)b * NN + q) * NN;
    const int tid  = threadIdx.x;
    const int lane = tid & 63;
    const int w    = tid >> 6;
    const int k0   = tid * 8;
    const bool active = k0 < Lp32;
    const float NEG = -__builtin_huge_valf();

    float f[8];
    if (active) {
        half8 v = *(const half8*)&S[base + k0];
        for (int j = 0; j < 8; ++j) f[j] = (k0 + j < L) ? (float)v[j] : NEG;
    } else {
        for (int j = 0; j < 8; ++j) f[j] = NEG;
    }

    float m = f[0];
    for (int j = 1; j < 8; ++j) m = fmaxf(m, f[j]);
    for (int off = 32; off > 0; off >>= 1) m = fmaxf(m, __shfl_xor(m, off));
    __shared__ float redm[4];
    __shared__ float reds[4];
    if (lane == 0) redm[w] = m;
    __syncthreads();
    m = fmaxf(fmaxf(redm[0], redm[1]), fmaxf(redm[2], redm[3]));

    float e[8], s = 0.f;
    for (int j = 0; j < 8; ++j) { e[j] = __expf(f[j] - m); s += e[j]; }  // exp(-inf)=0
    for (int off = 32; off > 0; off >>= 1) s += __shfl_xor(s, off);
    if (lane == 0) reds[w] = s;
    __syncthreads();
    s = (reds[0] + reds[1]) + (reds[2] + reds[3]);

    float inv = 1.0f / s;
    if (active) {
        half8 o;
        for (int j = 0; j < 8; ++j) o[j] = (_Float16)(e[j] * inv);
        *(half8*)&S[base + k0] = o;
    }
}

// ---------------------------------------------------------------------------
// Kernel 4: O[b][q][e] = sum_{k<L} P[b][q][k] * Vt[b][e][k].  K-loop only
// ceil(L/32) iterations; blocks with r0>=L exit (rows q>=L filled later).
// ---------------------------------------------------------------------------
__global__ __launch_bounds__(256) void pv_kernel(
    const _Float16* __restrict__ P, const _Float16* __restrict__ vhT,
    const int* __restrict__ lens, float* __restrict__ out)
{
    const int b  = blockIdx.z;
    const int L  = lens[b];
    const int r0 = blockIdx.y * 128;   // q rows
    if (r0 >= L) return;
    const int c0 = blockIdx.x * 128;   // e cols
    const int KT = (L + 31) >> 5;
    const _Float16* A  = P   + (size_t)b * NN * NN;
    const _Float16* Vh = vhT + (size_t)b * DD * NN;

    __shared__ __align__(16) _Float16 As[128 * 32];
    __shared__ __align__(16) _Float16 Bhs[128 * 32];

    const int tid  = threadIdx.x;
    const int lane = tid & 63;
    const int w    = tid >> 6;
    const int wm   = w >> 1, wn = w & 1;
    const int lr   = lane & 15;
    const int quad = lane >> 4;

    floatx4 zero; zero[0]=0.f; zero[1]=0.f; zero[2]=0.f; zero[3]=0.f;
    floatx4 acc[4][4];
    for (int i = 0; i < 4; ++i)
        for (int j = 0; j < 4; ++j) acc[i][j] = zero;

    for (int kt = 0; kt < KT; ++kt) {
        __syncthreads();
        stage_tile(A  + (size_t)r0 * NN + kt * 32, NN, As,  w, lane);
        stage_tile(Vh + (size_t)c0 * NN + kt * 32, NN, Bhs, w, lane);
        __syncthreads();

        half8 a[4], bh[4];
        for (int mt = 0; mt < 4; ++mt) a[mt]  = frag(As,  wm * 64 + mt * 16 + lr, quad);
        for (int nt = 0; nt < 4; ++nt) bh[nt] = frag(Bhs, wn * 64 + nt * 16 + lr, quad);
        for (int mt = 0; mt < 4; ++mt)
            for (int nt = 0; nt < 4; ++nt)
                acc[mt][nt] = __builtin_amdgcn_mfma_f32_16x16x32_f16(a[mt], bh[nt], acc[mt][nt], 0, 0, 0);
    }

    for (int mt = 0; mt < 4; ++mt)
        for (int nt = 0; nt < 4; ++nt)
            for (int r = 0; r < 4; ++r) {
                int q = r0 + wm * 64 + mt * 16 + quad * 4 + r;
                int e = c0 + wn * 64 + nt * 16 + lr;
                out[((size_t)b * NN + q) * DD + e] = acc[mt][nt][r];
            }
}

// ---------------------------------------------------------------------------
// Kernel 5: rows q>=L get the exact uniform-softmax output mean_v.
// ---------------------------------------------------------------------------
__global__ __launch_bounds__(128) void fill_kernel(
    const float* __restrict__ mean_v, const int* __restrict__ lens,
    float* __restrict__ out)
{
    const int b = blockIdx.y, q = blockIdx.x;
    if (q < lens[b]) return;
    const int e = threadIdx.x * 4;
    float4v m = *(const float4v*)&mean_v[b * DD + e];
    *(float4v*)&out[((size_t)b * NN + q) * DD + e] = m;
}

// ---------------------------------------------------------------------------
extern "C" void kernel_launch(void* const* d_in, const int* in_sizes, int n_in,
                              void* d_out, int out_size, void* d_ws, size_t ws_size,
                              hipStream_t stream) {
    const float* x    = (const float*)d_in[0];
    const int*   lens = (const int*)d_in[1];   // harness delivers integer inputs as int32
    const float* Wq   = (const float*)d_in[2];
    const float* bq   = (const float*)d_in[3];
    const float* Wk   = (const float*)d_in[4];
    const float* bk   = (const float*)d_in[5];
    const float* Wv   = (const float*)d_in[6];
    const float* bv   = (const float*)d_in[7];
    float* out = (float*)d_out;

    // workspace layout (128 MiB):
    //   0:    qb (16M) | 16M: kb (16M) | 32M: vhT (16M) | 48M: mean_v (16K)
    //   64M:  S (64M) — first ~18M overlaid by [xh 16M | wqh | wkh | wvh],
    //         dead before scores_kernel writes S (stream-ordered).
    char* ws = (char*)d_ws;
    const size_t MB = 1024 * 1024;
    _Float16* qb  = (_Float16*)(ws);
    _Float16* kb  = (_Float16*)(ws + 16 * MB);
    _Float16* vh  = (_Float16*)(ws + 32 * MB);
    float*    mv  = (float*)   (ws + 48 * MB);
    _Float16* S   = (_Float16*)(ws + 64 * MB);
    _Float16* xh  = (_Float16*)(ws + 64 * MB);
    _Float16* wqh = (_Float16*)(ws + 80 * MB);
    _Float16* wkh = (_Float16*)(ws + 80 * MB + 512 * 1024);
    _Float16* wvh = (_Float16*)(ws + 81 * MB);

    prep_kernel  <<<8960, 256, 0, stream>>>(x, Wq, Wk, Wv, xh, wqh, wkh, wvh);
    projqk_kernel<<<dim3(4, 128, 2), 256, 0, stream>>>(xh, wqh, wkh, bq, bk, lens, qb, kb);
    projv_kernel <<<dim3(16, 4, 8),  256, 0, stream>>>(xh, wvh, bv, vh);
    meanv_kernel <<<dim3(512, 8),    256, 0, stream>>>(vh, mv);
    scores_kernel<<<dim3(16, 16, 8), 256, 0, stream>>>(qb, kb, lens, S);
    softmax_kernel<<<dim3(2048, 8),  256, 0, stream>>>(S, lens);
    pv_kernel    <<<dim3(4, 16, 8),  256, 0, stream>>>(S, vh, lens, out);
    fill_kernel  <<<dim3(2048, 8),   128, 0, stream>>>(mv, lens, out);
}

// Round 7
// 211.583 us; speedup vs baseline: 2.6935x; 1.0450x over previous
//
#include <hip/hip_runtime.h>

typedef _Float16 half8 __attribute__((ext_vector_type(8)));
typedef _Float16 half4 __attribute__((ext_vector_type(4)));
typedef float    floatx4 __attribute__((ext_vector_type(4)));
typedef float    float4v __attribute__((ext_vector_type(4)));

#define BB 8
#define NN 2048
#define DD 512

// MFMA fragment mapping (gfx950, 16x16x32, m89/m91/m120-verified):
//   A-operand: A[m = lane&15][k = (lane>>4)*8 + j], j=0..7 contiguous
//   B-operand: B[n = lane&15][k = (lane>>4)*8 + j]   (NT: both contiguous in k)
//   C/D:       col = lane&15, row = (lane>>4)*4 + reg
//
// m97-style staging: unpadded [rows][32] fp16 LDS tiles filled by
// global_load_lds width=16.  XOR swizzle: 16B block c of row r lives at
// physical block c ^ ((r>>1)&3).  R4-R6 measured: SQ_LDS_BANK_CONFLICT == 0.
//
// Length-aware sparsity: only the (q<L)x(k<L) region is computed.  Rows
// q>=L get mean(v) exactly (uniform softmax over equal sentinels), written
// in pv's epilogue (R7: fill folded into pv; pv q-tile halved to 64 rows to
// get ~2 GEMM-active blocks/CU instead of ~1 -> latency overlap).

__device__ __forceinline__ void stage_tile(const _Float16* __restrict__ g,
                                           int gstride, _Float16* lds,
                                           int w, int lane)
{
#pragma unroll
    for (int j = 0; j < 2; ++j) {
        int grp = w * 2 + j;                      // 16-row group 0..7
        int r   = grp * 16 + (lane >> 2);         // 0..127
        int cb  = (lane & 3) ^ ((r >> 1) & 3);    // logical 16B block to fetch
        const _Float16* gp = g + (size_t)r * gstride + cb * 8;
        _Float16* lp = lds + grp * 512;           // wave-uniform base
        __builtin_amdgcn_global_load_lds(
            (const __attribute__((address_space(1))) void*)gp,
            (__attribute__((address_space(3))) void*)lp, 16, 0, 0);
    }
}

// 64-row variant: one load per thread.
__device__ __forceinline__ void stage_tile64(const _Float16* __restrict__ g,
                                             int gstride, _Float16* lds,
                                             int w, int lane)
{
    int r  = w * 16 + (lane >> 2);                // 0..63
    int cb = (lane & 3) ^ ((r >> 1) & 3);
    const _Float16* gp = g + (size_t)r * gstride + cb * 8;
    _Float16* lp = lds + w * 512;                 // wave-uniform base
    __builtin_amdgcn_global_load_lds(
        (const __attribute__((address_space(1))) void*)gp,
        (__attribute__((address_space(3))) void*)lp, 16, 0, 0);
}

__device__ __forceinline__ half8 frag(const _Float16* tile, int m, int quad)
{
    return *(const half8*)&tile[m * 32 + ((quad ^ ((m >> 1) & 3)) * 8)];
}

// ---------------------------------------------------------------------------
// Kernel 0: prep — fp16 copies of x, Wq, Wk, Wv.
// ---------------------------------------------------------------------------
__global__ __launch_bounds__(256) void prep_kernel(
    const float* __restrict__ x, const float* __restrict__ Wq,
    const float* __restrict__ Wk, const float* __restrict__ Wv,
    _Float16* __restrict__ xh, _Float16* __restrict__ wqh,
    _Float16* __restrict__ wkh, _Float16* __restrict__ wvh)
{
    const int XQ = (BB * NN * DD) / 4;   // 2097152 float4s
    const int WQ = (DD * DD) / 4;        // 65536
    int t = blockIdx.x * 256 + threadIdx.x;
    const float* src; _Float16* dst; int i;
    if (t < XQ)             { src = x;  dst = xh;  i = t; }
    else if (t < XQ + WQ)   { src = Wq; dst = wqh; i = t - XQ; }
    else if (t < XQ + 2*WQ) { src = Wk; dst = wkh; i = t - XQ - WQ; }
    else if (t < XQ + 3*WQ) { src = Wv; dst = wvh; i = t - XQ - 2*WQ; }
    else return;
    float4v f = *(const float4v*)&src[(size_t)i * 4];
    half4 h;
    for (int j = 0; j < 4; ++j) h[j] = (_Float16)f[j];
    *(half4*)&dst[(size_t)i * 4] = h;
}

// ---------------------------------------------------------------------------
// Kernel 1: Q/K projection (fp16 inputs, m97 staging).  Blocks whose row
// tile (within its batch) starts >= L are never read downstream -> exit.
// ---------------------------------------------------------------------------
__global__ __launch_bounds__(256) void projqk_kernel(
    const _Float16* __restrict__ xh,
    const _Float16* __restrict__ wqh, const _Float16* __restrict__ wkh,
    const float* __restrict__ bq, const float* __restrict__ bk,
    const int* __restrict__ lens,
    _Float16* __restrict__ qb, _Float16* __restrict__ kb)
{
    const int z = blockIdx.z;                       // 0=q 1=k
    const int r0 = blockIdx.y * 128;                // global row in [0,16384)
    const int bb = r0 >> 11;                        // batch
    if ((r0 & 2047) >= lens[bb]) return;            // rows never read
    const _Float16* Wh  = z ? wkh : wqh;
    const float*    bias= z ? bk  : bq;
    _Float16*       outp= z ? kb  : qb;
    const int c0 = blockIdx.x * 128;

    __shared__ __align__(16) _Float16 As[128 * 32];
    __shared__ __align__(16) _Float16 Bs[128 * 32];

    const int tid  = threadIdx.x;
    const int lane = tid & 63;
    const int w    = tid >> 6;
    const int wm   = w >> 1, wn = w & 1;
    const int lr   = lane & 15;
    const int quad = lane >> 4;

    floatx4 zero; zero[0]=0.f; zero[1]=0.f; zero[2]=0.f; zero[3]=0.f;
    floatx4 acc[4][4];
    for (int i = 0; i < 4; ++i)
        for (int j = 0; j < 4; ++j) acc[i][j] = zero;

    for (int kt = 0; kt < DD / 32; ++kt) {
        __syncthreads();
        stage_tile(xh + (size_t)r0 * DD + kt * 32, DD, As, w, lane);
        stage_tile(Wh + (size_t)c0 * DD + kt * 32, DD, Bs, w, lane);
        __syncthreads();
        half8 a[4], b[4];
        for (int mt = 0; mt < 4; ++mt) a[mt] = frag(As, wm * 64 + mt * 16 + lr, quad);
        for (int nt = 0; nt < 4; ++nt) b[nt] = frag(Bs, wn * 64 + nt * 16 + lr, quad);
        for (int mt = 0; mt < 4; ++mt)
            for (int nt = 0; nt < 4; ++nt)
                acc[mt][nt] = __builtin_amdgcn_mfma_f32_16x16x32_f16(a[mt], b[nt], acc[mt][nt], 0, 0, 0);
    }

    for (int mt = 0; mt < 4; ++mt)
        for (int nt = 0; nt < 4; ++nt)
            for (int r = 0; r < 4; ++r) {
                int row = r0 + wm * 64 + mt * 16 + quad * 4 + r;
                int col = c0 + wn * 64 + nt * 16 + lr;
                outp[(size_t)row * DD + col] = (_Float16)(acc[mt][nt][r] + bias[col]);
            }
}

// ---------------------------------------------------------------------------
// Kernel 1b: V projection, TRANSPOSED output (all rows needed: mean_v spans
// all n).  Vt[b][e][n] = sum_d wvh[e][d] * xh[b,n][d].
// ---------------------------------------------------------------------------
__global__ __launch_bounds__(256) void projv_kernel(
    const _Float16* __restrict__ xh,
    const _Float16* __restrict__ wvh, const float* __restrict__ bv,
    _Float16* __restrict__ vhT)
{
    const int b  = blockIdx.z;
    const int e0 = blockIdx.y * 128;
    const int n0 = blockIdx.x * 128;

    __shared__ __align__(16) _Float16 As[128 * 32];
    __shared__ __align__(16) _Float16 Bs[128 * 32];

    const int tid  = threadIdx.x;
    const int lane = tid & 63;
    const int w    = tid >> 6;
    const int wm   = w >> 1, wn = w & 1;
    const int lr   = lane & 15;
    const int quad = lane >> 4;

    floatx4 zero; zero[0]=0.f; zero[1]=0.f; zero[2]=0.f; zero[3]=0.f;
    floatx4 acc[4][4];
    for (int i = 0; i < 4; ++i)
        for (int j = 0; j < 4; ++j) acc[i][j] = zero;

    for (int kt = 0; kt < DD / 32; ++kt) {
        __syncthreads();
        stage_tile(wvh + (size_t)e0 * DD + kt * 32, DD, As, w, lane);
        stage_tile(xh + ((size_t)b * NN + n0) * DD + kt * 32, DD, Bs, w, lane);
        __syncthreads();
        half8 a[4], bfr[4];
        for (int mt = 0; mt < 4; ++mt) a[mt]   = frag(As, wm * 64 + mt * 16 + lr, quad);
        for (int nt = 0; nt < 4; ++nt) bfr[nt] = frag(Bs, wn * 64 + nt * 16 + lr, quad);
        for (int mt = 0; mt < 4; ++mt)
            for (int nt = 0; nt < 4; ++nt)
                acc[mt][nt] = __builtin_amdgcn_mfma_f32_16x16x32_f16(a[mt], bfr[nt], acc[mt][nt], 0, 0, 0);
    }

    for (int mt = 0; mt < 4; ++mt)
        for (int nt = 0; nt < 4; ++nt)
            for (int r = 0; r < 4; ++r) {
                int e = e0 + wm * 64 + mt * 16 + quad * 4 + r;
                int n = n0 + wn * 64 + nt * 16 + lr;
                vhT[((size_t)b * DD + e) * NN + n] = (_Float16)(acc[mt][nt][r] + bv[e]);
            }
}

// ---------------------------------------------------------------------------
// Kernel 1c: mean_v[b][e] = (1/2048) sum_n Vt[b][e][n]  (one block per row).
// Exact value of the reference's masked-query rows (uniform softmax).
// ---------------------------------------------------------------------------
__global__ __launch_bounds__(256) void meanv_kernel(
    const _Float16* __restrict__ vhT, float* __restrict__ mean_v)
{
    const int b = blockIdx.y, e = blockIdx.x;
    const _Float16* row = vhT + ((size_t)b * DD + e) * NN;
    const int tid  = threadIdx.x;
    const int lane = tid & 63;
    const int w    = tid >> 6;

    half8 v = *(const half8*)&row[tid * 8];
    float s = 0.f;
    for (int j = 0; j < 8; ++j) s += (float)v[j];
    for (int off = 32; off > 0; off >>= 1) s += __shfl_xor(s, off);
    __shared__ float red[4];
    if (lane == 0) red[w] = s;
    __syncthreads();
    if (tid == 0)
        mean_v[b * DD + e] = (red[0] + red[1] + red[2] + red[3]) * (1.0f / 2048.0f);
}

// ---------------------------------------------------------------------------
// Kernel 2: S = (Q.K^T)/sqrt(512) -> fp16, only tiles with r0<L && c0<L.
// ---------------------------------------------------------------------------
__global__ __launch_bounds__(256) void scores_kernel(
    const _Float16* __restrict__ qb, const _Float16* __restrict__ kb,
    const int* __restrict__ lens, _Float16* __restrict__ S)
{
    const int b  = blockIdx.z;
    const int r0 = blockIdx.y * 128;
    const int c0 = blockIdx.x * 128;
    const int L  = lens[b];
    if (r0 >= L || c0 >= L) return;
    const _Float16* A  = qb + (size_t)b * NN * DD;
    const _Float16* Bm = kb + (size_t)b * NN * DD;

    __shared__ __align__(16) _Float16 As[128 * 32];
    __shared__ __align__(16) _Float16 Bs[128 * 32];

    const int tid  = threadIdx.x;
    const int lane = tid & 63;
    const int w    = tid >> 6;
    const int wm   = w >> 1, wn = w & 1;
    const int lr   = lane & 15;
    const int quad = lane >> 4;

    floatx4 zero; zero[0]=0.f; zero[1]=0.f; zero[2]=0.f; zero[3]=0.f;
    floatx4 acc[4][4];
    for (int i = 0; i < 4; ++i)
        for (int j = 0; j < 4; ++j) acc[i][j] = zero;

    for (int kt = 0; kt < DD / 32; ++kt) {
        __syncthreads();
        stage_tile(A  + (size_t)r0 * DD + kt * 32, DD, As, w, lane);
        stage_tile(Bm + (size_t)c0 * DD + kt * 32, DD, Bs, w, lane);
        __syncthreads();
        half8 a[4], bfr[4];
        for (int mt = 0; mt < 4; ++mt) a[mt]   = frag(As, wm * 64 + mt * 16 + lr, quad);
        for (int nt = 0; nt < 4; ++nt) bfr[nt] = frag(Bs, wn * 64 + nt * 16 + lr, quad);
        for (int mt = 0; mt < 4; ++mt)
            for (int nt = 0; nt < 4; ++nt)
                acc[mt][nt] = __builtin_amdgcn_mfma_f32_16x16x32_f16(a[mt], bfr[nt], acc[mt][nt], 0, 0, 0);
    }

    const float scale = 0.044194173824159216f;   // 1/sqrt(512)
    for (int mt = 0; mt < 4; ++mt)
        for (int nt = 0; nt < 4; ++nt)
            for (int r = 0; r < 4; ++r) {
                int q    = r0 + wm * 64 + mt * 16 + quad * 4 + r;
                int kcol = c0 + wn * 64 + nt * 16 + lr;
                S[((size_t)b * NN + q) * NN + kcol] = (_Float16)(acc[mt][nt][r] * scale);
            }
}

// ---------------------------------------------------------------------------
// Kernel 3: in-place row softmax, rows q<L only, keys k<L only; writes P=0
// for k in [L, ceil32(L)) so pv's last K-chunk is clean.
// ---------------------------------------------------------------------------
__global__ __launch_bounds__(256) void softmax_kernel(
    _Float16* __restrict__ S, const int* __restrict__ lens)
{
    const int b = blockIdx.y, q = blockIdx.x;
    const int L = lens[b];
    if (q >= L) return;
    const int Lp32 = (L + 31) & ~31;
    const size_t base = ((size_t)b * NN + q) * NN;
    const int tid  = threadIdx.x;
    const int lane = tid & 63;
    const int w    = tid >> 6;
    const int k0   = tid * 8;
    const bool active = k0 < Lp32;
    const float NEG = -__builtin_huge_valf();

    float f[8];
    if (active) {
        half8 v = *(const half8*)&S[base + k0];
        for (int j = 0; j < 8; ++j) f[j] = (k0 + j < L) ? (float)v[j] : NEG;
    } else {
        for (int j = 0; j < 8; ++j) f[j] = NEG;
    }

    float m = f[0];
    for (int j = 1; j < 8; ++j) m = fmaxf(m, f[j]);
    for (int off = 32; off > 0; off >>= 1) m = fmaxf(m, __shfl_xor(m, off));
    __shared__ float redm[4];
    __shared__ float reds[4];
    if (lane == 0) redm[w] = m;
    __syncthreads();
    m = fmaxf(fmaxf(redm[0], redm[1]), fmaxf(redm[2], redm[3]));

    float e[8], s = 0.f;
    for (int j = 0; j < 8; ++j) { e[j] = __expf(f[j] - m); s += e[j]; }  // exp(-inf)=0
    for (int off = 32; off > 0; off >>= 1) s += __shfl_xor(s, off);
    if (lane == 0) reds[w] = s;
    __syncthreads();
    s = (reds[0] + reds[1]) + (reds[2] + reds[3]);

    float inv = 1.0f / s;
    if (active) {
        half8 o;
        for (int j = 0; j < 8; ++j) o[j] = (_Float16)(e[j] * inv);
        *(half8*)&S[base + k0] = o;
    }
}

// ---------------------------------------------------------------------------
// Kernel 4: O[b][q][e] = sum_{k<L} P[b][q][k] * Vt[b][e][k] for q<L;
// mean_v[b][e] for q>=L (fill folded in).  64-row q-tiles for ~2 GEMM-active
// blocks/CU (latency overlap).  4 waves, each 64 rows x 32 cols (4m x 2n).
// ---------------------------------------------------------------------------
__global__ __launch_bounds__(256) void pv_kernel(
    const _Float16* __restrict__ P, const _Float16* __restrict__ vhT,
    const int* __restrict__ lens, const float* __restrict__ mean_v,
    float* __restrict__ out)
{
    const int b  = blockIdx.z;
    const int L  = lens[b];
    const int r0 = blockIdx.y * 64;    // q rows (64-row tiles)
    const int c0 = blockIdx.x * 128;   // e cols
    const int KT = (r0 < L) ? ((L + 31) >> 5) : 0;
    const _Float16* A  = P   + (size_t)b * NN * NN;
    const _Float16* Vh = vhT + (size_t)b * DD * NN;

    __shared__ __align__(16) _Float16 As[64 * 32];
    __shared__ __align__(16) _Float16 Bhs[128 * 32];

    const int tid  = threadIdx.x;
    const int lane = tid & 63;
    const int w    = tid >> 6;
    const int lr   = lane & 15;
    const int quad = lane >> 4;

    floatx4 zero; zero[0]=0.f; zero[1]=0.f; zero[2]=0.f; zero[3]=0.f;
    floatx4 acc[4][2];
    for (int i = 0; i < 4; ++i)
        for (int j = 0; j < 2; ++j) acc[i][j] = zero;

    for (int kt = 0; kt < KT; ++kt) {
        __syncthreads();
        stage_tile64(A + (size_t)r0 * NN + kt * 32, NN, As, w, lane);
        stage_tile (Vh + (size_t)c0 * NN + kt * 32, NN, Bhs, w, lane);
        __syncthreads();

        half8 a[4], bh[2];
        for (int mt = 0; mt < 4; ++mt) a[mt]  = frag(As, mt * 16 + lr, quad);
        for (int nt = 0; nt < 2; ++nt) bh[nt] = frag(Bhs, w * 32 + nt * 16 + lr, quad);
        for (int mt = 0; mt < 4; ++mt)
            for (int nt = 0; nt < 2; ++nt)
                acc[mt][nt] = __builtin_amdgcn_mfma_f32_16x16x32_f16(a[mt], bh[nt], acc[mt][nt], 0, 0, 0);
    }

    float mval[2];
    for (int nt = 0; nt < 2; ++nt)
        mval[nt] = mean_v[b * DD + c0 + w * 32 + nt * 16 + lr];

    for (int mt = 0; mt < 4; ++mt)
        for (int nt = 0; nt < 2; ++nt)
            for (int r = 0; r < 4; ++r) {
                int q = r0 + mt * 16 + quad * 4 + r;
                int e = c0 + w * 32 + nt * 16 + lr;
                float val = (q < L) ? acc[mt][nt][r] : mval[nt];
                out[((size_t)b * NN + q) * DD + e] = val;
            }
}

// ---------------------------------------------------------------------------
extern "C" void kernel_launch(void* const* d_in, const int* in_sizes, int n_in,
                              void* d_out, int out_size, void* d_ws, size_t ws_size,
                              hipStream_t stream) {
    const float* x    = (const float*)d_in[0];
    const int*   lens = (const int*)d_in[1];   // harness delivers integer inputs as int32
    const float* Wq   = (const float*)d_in[2];
    const float* bq   = (const float*)d_in[3];
    const float* Wk   = (const float*)d_in[4];
    const float* bk   = (const float*)d_in[5];
    const float* Wv   = (const float*)d_in[6];
    const float* bv   = (const float*)d_in[7];
    float* out = (float*)d_out;

    // workspace layout (128 MiB):
    //   0:    qb (16M) | 16M: kb (16M) | 32M: vhT (16M) | 48M: mean_v (16K)
    //   64M:  S (64M) — first ~18M overlaid by [xh 16M | wqh | wkh | wvh],
    //         dead before scores_kernel writes S (stream-ordered).
    char* ws = (char*)d_ws;
    const size_t MB = 1024 * 1024;
    _Float16* qb  = (_Float16*)(ws);
    _Float16* kb  = (_Float16*)(ws + 16 * MB);
    _Float16* vh  = (_Float16*)(ws + 32 * MB);
    float*    mv  = (float*)   (ws + 48 * MB);
    _Float16* S   = (_Float16*)(ws + 64 * MB);
    _Float16* xh  = (_Float16*)(ws + 64 * MB);
    _Float16* wqh = (_Float16*)(ws + 80 * MB);
    _Float16* wkh = (_Float16*)(ws + 80 * MB + 512 * 1024);
    _Float16* wvh = (_Float16*)(ws + 81 * MB);

    prep_kernel  <<<8960, 256, 0, stream>>>(x, Wq, Wk, Wv, xh, wqh, wkh, wvh);
    projqk_kernel<<<dim3(4, 128, 2), 256, 0, stream>>>(xh, wqh, wkh, bq, bk, lens, qb, kb);
    projv_kernel <<<dim3(16, 4, 8),  256, 0, stream>>>(xh, wvh, bv, vh);
    meanv_kernel <<<dim3(512, 8),    256, 0, stream>>>(vh, mv);
    scores_kernel<<<dim3(16, 16, 8), 256, 0, stream>>>(qb, kb, lens, S);
    softmax_kernel<<<dim3(2048, 8),  256, 0, stream>>>(S, lens);
    pv_kernel    <<<dim3(4, 32, 8),  256, 0, stream>>>(S, vh, lens, mv, out);
}

// Round 8
// 211.009 us; speedup vs baseline: 2.7008x; 1.0027x over previous
//
#include <hip/hip_runtime.h>

typedef _Float16 half8 __attribute__((ext_vector_type(8)));
typedef _Float16 half4 __attribute__((ext_vector_type(4)));
typedef float    floatx4 __attribute__((ext_vector_type(4)));
typedef float    float4v __attribute__((ext_vector_type(4)));

#define BB 8
#define NN 2048
#define DD 512

// MFMA fragment mapping (gfx950, 16x16x32, m89/m91/m120-verified):
//   A-operand: A[m = lane&15][k = (lane>>4)*8 + j], j=0..7 contiguous
//   B-operand: B[n = lane&15][k = (lane>>4)*8 + j]   (NT: both contiguous in k)
//   C/D:       col = lane&15, row = (lane>>4)*4 + reg
//
// m97-style staging: unpadded [rows][32] fp16 LDS tiles filled by
// global_load_lds width=16.  XOR swizzle: 16B block c of row r lives at
// physical block c ^ ((r>>1)&3).  R4-R7 measured: SQ_LDS_BANK_CONFLICT == 0.
//
// Length-aware sparsity: only the (q<L)x(k<L) region is computed.  Rows
// q>=L get mean(v) exactly; R8: mean_v = Wv*mean_x + bv (linearity) so
// projv skips n0>=L tiles and meanv's 32MB pass is gone.  pv is
// double-buffered: next tile's loads fly during current tile's MFMAs.

__device__ __forceinline__ void stage_tile(const _Float16* __restrict__ g,
                                           int gstride, _Float16* lds,
                                           int w, int lane)
{
#pragma unroll
    for (int j = 0; j < 2; ++j) {
        int grp = w * 2 + j;                      // 16-row group 0..7
        int r   = grp * 16 + (lane >> 2);         // 0..127
        int cb  = (lane & 3) ^ ((r >> 1) & 3);    // logical 16B block to fetch
        const _Float16* gp = g + (size_t)r * gstride + cb * 8;
        _Float16* lp = lds + grp * 512;           // wave-uniform base
        __builtin_amdgcn_global_load_lds(
            (const __attribute__((address_space(1))) void*)gp,
            (__attribute__((address_space(3))) void*)lp, 16, 0, 0);
    }
}

// 64-row variant: one load per thread.
__device__ __forceinline__ void stage_tile64(const _Float16* __restrict__ g,
                                             int gstride, _Float16* lds,
                                             int w, int lane)
{
    int r  = w * 16 + (lane >> 2);                // 0..63
    int cb = (lane & 3) ^ ((r >> 1) & 3);
    const _Float16* gp = g + (size_t)r * gstride + cb * 8;
    _Float16* lp = lds + w * 512;                 // wave-uniform base
    __builtin_amdgcn_global_load_lds(
        (const __attribute__((address_space(1))) void*)gp,
        (__attribute__((address_space(3))) void*)lp, 16, 0, 0);
}

__device__ __forceinline__ half8 frag(const _Float16* tile, int m, int quad)
{
    return *(const half8*)&tile[m * 32 + ((quad ^ ((m >> 1) & 3)) * 8)];
}

// ---------------------------------------------------------------------------
// Kernel 0: prep — fp16 copies of x, Wq, Wk, Wv.  x rows >= ceil128(L) are
// never read by projqk/projv -> skipped.
// ---------------------------------------------------------------------------
__global__ __launch_bounds__(256) void prep_kernel(
    const float* __restrict__ x, const float* __restrict__ Wq,
    const float* __restrict__ Wk, const float* __restrict__ Wv,
    const int* __restrict__ lens,
    _Float16* __restrict__ xh, _Float16* __restrict__ wqh,
    _Float16* __restrict__ wkh, _Float16* __restrict__ wvh)
{
    const int XQ = (BB * NN * DD) / 4;   // 2097152 float4s
    const int WQ = (DD * DD) / 4;        // 65536
    int t = blockIdx.x * 256 + threadIdx.x;
    const float* src; _Float16* dst; int i;
    if (t < XQ) {
        int row = t >> 7;                // 512 floats = 128 float4 per row
        int b   = row >> 11;
        if ((row & 2047) >= ((lens[b] + 127) & ~127)) return;
        src = x;  dst = xh;  i = t;
    }
    else if (t < XQ + WQ)   { src = Wq; dst = wqh; i = t - XQ; }
    else if (t < XQ + 2*WQ) { src = Wk; dst = wkh; i = t - XQ - WQ; }
    else if (t < XQ + 3*WQ) { src = Wv; dst = wvh; i = t - XQ - 2*WQ; }
    else return;
    float4v f = *(const float4v*)&src[(size_t)i * 4];
    half4 h;
    for (int j = 0; j < 4; ++j) h[j] = (_Float16)f[j];
    *(half4*)&dst[(size_t)i * 4] = h;
}

// ---------------------------------------------------------------------------
// Kernel 0b: column sums of x (fp32, exact): sx[b][d] = sum_n x[b][n][d].
// mx pre-zeroed by hipMemsetAsync.  Mean is over ALL n (no pruning).
// ---------------------------------------------------------------------------
__global__ __launch_bounds__(256) void meanx_kernel(
    const float* __restrict__ x, float* __restrict__ sx)
{
    const int b  = blockIdx.y;
    const int n0 = blockIdx.x * 64;
    const int d0 = threadIdx.x;          // 0..255; also handles d0+256
    float s0 = 0.f, s1 = 0.f;
    const float* base = x + ((size_t)b * NN + n0) * DD;
    for (int n = 0; n < 64; ++n) {
        s0 += base[n * DD + d0];
        s1 += base[n * DD + d0 + 256];
    }
    atomicAdd(&sx[b * DD + d0], s0);
    atomicAdd(&sx[b * DD + d0 + 256], s1);
}

// ---------------------------------------------------------------------------
// Kernel 0c: mean_v[b][e] = Wv[e,:].(sx[b,:]/2048) + bv[e]   (fp32, exact
// value of the reference's masked-query rows by linearity of the mean).
// One wave per output; 4 outputs per block.
// ---------------------------------------------------------------------------
__global__ __launch_bounds__(256) void mvgemv_kernel(
    const float* __restrict__ Wv, const float* __restrict__ bv,
    const float* __restrict__ sx, float* __restrict__ mean_v)
{
    const int blk = blockIdx.x;          // 0..1023
    const int b   = blk >> 7;
    const int e   = (blk & 127) * 4 + (threadIdx.x >> 6);
    const int lane = threadIdx.x & 63;
    const float* wr = Wv + (size_t)e * DD + lane * 8;
    const float* xr = sx + b * DD + lane * 8;
    float s = 0.f;
    for (int j = 0; j < 8; ++j) s += wr[j] * xr[j];
    for (int off = 32; off > 0; off >>= 1) s += __shfl_xor(s, off);
    if (lane == 0)
        mean_v[b * DD + e] = s * (1.0f / 2048.0f) + bv[e];
}

// ---------------------------------------------------------------------------
// Kernel 1: Q/K projection (fp16 inputs, m97 staging).  Blocks whose row
// tile (within its batch) starts >= L are never read downstream -> exit.
// ---------------------------------------------------------------------------
__global__ __launch_bounds__(256) void projqk_kernel(
    const _Float16* __restrict__ xh,
    const _Float16* __restrict__ wqh, const _Float16* __restrict__ wkh,
    const float* __restrict__ bq, const float* __restrict__ bk,
    const int* __restrict__ lens,
    _Float16* __restrict__ qb, _Float16* __restrict__ kb)
{
    const int z = blockIdx.z;                       // 0=q 1=k
    const int r0 = blockIdx.y * 128;                // global row in [0,16384)
    const int bb = r0 >> 11;                        // batch
    if ((r0 & 2047) >= lens[bb]) return;            // rows never read
    const _Float16* Wh  = z ? wkh : wqh;
    const float*    bias= z ? bk  : bq;
    _Float16*       outp= z ? kb  : qb;
    const int c0 = blockIdx.x * 128;

    __shared__ __align__(16) _Float16 As[128 * 32];
    __shared__ __align__(16) _Float16 Bs[128 * 32];

    const int tid  = threadIdx.x;
    const int lane = tid & 63;
    const int w    = tid >> 6;
    const int wm   = w >> 1, wn = w & 1;
    const int lr   = lane & 15;
    const int quad = lane >> 4;

    floatx4 zero; zero[0]=0.f; zero[1]=0.f; zero[2]=0.f; zero[3]=0.f;
    floatx4 acc[4][4];
    for (int i = 0; i < 4; ++i)
        for (int j = 0; j < 4; ++j) acc[i][j] = zero;

    for (int kt = 0; kt < DD / 32; ++kt) {
        __syncthreads();
        stage_tile(xh + (size_t)r0 * DD + kt * 32, DD, As, w, lane);
        stage_tile(Wh + (size_t)c0 * DD + kt * 32, DD, Bs, w, lane);
        __syncthreads();
        half8 a[4], b[4];
        for (int mt = 0; mt < 4; ++mt) a[mt] = frag(As, wm * 64 + mt * 16 + lr, quad);
        for (int nt = 0; nt < 4; ++nt) b[nt] = frag(Bs, wn * 64 + nt * 16 + lr, quad);
        for (int mt = 0; mt < 4; ++mt)
            for (int nt = 0; nt < 4; ++nt)
                acc[mt][nt] = __builtin_amdgcn_mfma_f32_16x16x32_f16(a[mt], b[nt], acc[mt][nt], 0, 0, 0);
    }

    for (int mt = 0; mt < 4; ++mt)
        for (int nt = 0; nt < 4; ++nt)
            for (int r = 0; r < 4; ++r) {
                int row = r0 + wm * 64 + mt * 16 + quad * 4 + r;
                int col = c0 + wn * 64 + nt * 16 + lr;
                outp[(size_t)row * DD + col] = (_Float16)(acc[mt][nt][r] + bias[col]);
            }
}

// ---------------------------------------------------------------------------
// Kernel 1b: V projection, TRANSPOSED output, tiles with n0 < L only
// (pv reads k < ceil32(L) <= ceil128(L), covered by straddle tiles).
// Vt[b][e][n] = sum_d wvh[e][d] * xh[b,n][d].
// ---------------------------------------------------------------------------
__global__ __launch_bounds__(256) void projv_kernel(
    const _Float16* __restrict__ xh,
    const _Float16* __restrict__ wvh, const float* __restrict__ bv,
    const int* __restrict__ lens, _Float16* __restrict__ vhT)
{
    const int b  = blockIdx.z;
    const int e0 = blockIdx.y * 128;
    const int n0 = blockIdx.x * 128;
    if (n0 >= lens[b]) return;

    __shared__ __align__(16) _Float16 As[128 * 32];
    __shared__ __align__(16) _Float16 Bs[128 * 32];

    const int tid  = threadIdx.x;
    const int lane = tid & 63;
    const int w    = tid >> 6;
    const int wm   = w >> 1, wn = w & 1;
    const int lr   = lane & 15;
    const int quad = lane >> 4;

    floatx4 zero; zero[0]=0.f; zero[1]=0.f; zero[2]=0.f; zero[3]=0.f;
    floatx4 acc[4][4];
    for (int i = 0; i < 4; ++i)
        for (int j = 0; j < 4; ++j) acc[i][j] = zero;

    for (int kt = 0; kt < DD / 32; ++kt) {
        __syncthreads();
        stage_tile(wvh + (size_t)e0 * DD + kt * 32, DD, As, w, lane);
        stage_tile(xh + ((size_t)b * NN + n0) * DD + kt * 32, DD, Bs, w, lane);
        __syncthreads();
        half8 a[4], bfr[4];
        for (int mt = 0; mt < 4; ++mt) a[mt]   = frag(As, wm * 64 + mt * 16 + lr, quad);
        for (int nt = 0; nt < 4; ++nt) bfr[nt] = frag(Bs, wn * 64 + nt * 16 + lr, quad);
        for (int mt = 0; mt < 4; ++mt)
            for (int nt = 0; nt < 4; ++nt)
                acc[mt][nt] = __builtin_amdgcn_mfma_f32_16x16x32_f16(a[mt], bfr[nt], acc[mt][nt], 0, 0, 0);
    }

    for (int mt = 0; mt < 4; ++mt)
        for (int nt = 0; nt < 4; ++nt)
            for (int r = 0; r < 4; ++r) {
                int e = e0 + wm * 64 + mt * 16 + quad * 4 + r;
                int n = n0 + wn * 64 + nt * 16 + lr;
                vhT[((size_t)b * DD + e) * NN + n] = (_Float16)(acc[mt][nt][r] + bv[e]);
            }
}

// ---------------------------------------------------------------------------
// Kernel 2: S = (Q.K^T)/sqrt(512) -> fp16, only tiles with r0<L && c0<L.
// ---------------------------------------------------------------------------
__global__ __launch_bounds__(256) void scores_kernel(
    const _Float16* __restrict__ qb, const _Float16* __restrict__ kb,
    const int* __restrict__ lens, _Float16* __restrict__ S)
{
    const int b  = blockIdx.z;
    const int r0 = blockIdx.y * 128;
    const int c0 = blockIdx.x * 128;
    const int L  = lens[b];
    if (r0 >= L || c0 >= L) return;
    const _Float16* A  = qb + (size_t)b * NN * DD;
    const _Float16* Bm = kb + (size_t)b * NN * DD;

    __shared__ __align__(16) _Float16 As[128 * 32];
    __shared__ __align__(16) _Float16 Bs[128 * 32];

    const int tid  = threadIdx.x;
    const int lane = tid & 63;
    const int w    = tid >> 6;
    const int wm   = w >> 1, wn = w & 1;
    const int lr   = lane & 15;
    const int quad = lane >> 4;

    floatx4 zero; zero[0]=0.f; zero[1]=0.f; zero[2]=0.f; zero[3]=0.f;
    floatx4 acc[4][4];
    for (int i = 0; i < 4; ++i)
        for (int j = 0; j < 4; ++j) acc[i][j] = zero;

    for (int kt = 0; kt < DD / 32; ++kt) {
        __syncthreads();
        stage_tile(A  + (size_t)r0 * DD + kt * 32, DD, As, w, lane);
        stage_tile(Bm + (size_t)c0 * DD + kt * 32, DD, Bs, w, lane);
        __syncthreads();
        half8 a[4], bfr[4];
        for (int mt = 0; mt < 4; ++mt) a[mt]   = frag(As, wm * 64 + mt * 16 + lr, quad);
        for (int nt = 0; nt < 4; ++nt) bfr[nt] = frag(Bs, wn * 64 + nt * 16 + lr, quad);
        for (int mt = 0; mt < 4; ++mt)
            for (int nt = 0; nt < 4; ++nt)
                acc[mt][nt] = __builtin_amdgcn_mfma_f32_16x16x32_f16(a[mt], bfr[nt], acc[mt][nt], 0, 0, 0);
    }

    const float scale = 0.044194173824159216f;   // 1/sqrt(512)
    for (int mt = 0; mt < 4; ++mt)
        for (int nt = 0; nt < 4; ++nt)
            for (int r = 0; r < 4; ++r) {
                int q    = r0 + wm * 64 + mt * 16 + quad * 4 + r;
                int kcol = c0 + wn * 64 + nt * 16 + lr;
                S[((size_t)b * NN + q) * NN + kcol] = (_Float16)(acc[mt][nt][r] * scale);
            }
}

// ---------------------------------------------------------------------------
// Kernel 3: in-place row softmax, rows q<L only, keys k<L only; writes P=0
// for k in [L, ceil32(L)) so pv's last K-chunk is clean.
// ---------------------------------------------------------------------------
__global__ __launch_bounds__(256) void softmax_kernel(
    _Float16* __restrict__ S, const int* __restrict__ lens)
{
    const int b = blockIdx.y, q = blockIdx.x;
    const int L = lens[b];
    if (q >= L) return;
    const int Lp32 = (L + 31) & ~31;
    const size_t base = ((size_t)b * NN + q) * NN;
    const int tid  = threadIdx.x;
    const int lane = tid & 63;
    const int w    = tid >> 6;
    const int k0   = tid * 8;
    const bool active = k0 < Lp32;
    const float NEG = -__builtin_huge_valf();

    float f[8];
    if (active) {
        half8 v = *(const half8*)&S[base + k0];
        for (int j = 0; j < 8; ++j) f[j] = (k0 + j < L) ? (float)v[j] : NEG;
    } else {
        for (int j = 0; j < 8; ++j) f[j] = NEG;
    }

    float m = f[0];
    for (int j = 1; j < 8; ++j) m = fmaxf(m, f[j]);
    for (int off = 32; off > 0; off >>= 1) m = fmaxf(m, __shfl_xor(m, off));
    __shared__ float redm[4];
    __shared__ float reds[4];
    if (lane == 0) redm[w] = m;
    __syncthreads();
    m = fmaxf(fmaxf(redm[0], redm[1]), fmaxf(redm[2], redm[3]));

    float e[8], s = 0.f;
    for (int j = 0; j < 8; ++j) { e[j] = __expf(f[j] - m); s += e[j]; }  // exp(-inf)=0
    for (int off = 32; off > 0; off >>= 1) s += __shfl_xor(s, off);
    if (lane == 0) reds[w] = s;
    __syncthreads();
    s = (reds[0] + reds[1]) + (reds[2] + reds[3]);

    float inv = 1.0f / s;
    if (active) {
        half8 o;
        for (int j = 0; j < 8; ++j) o[j] = (_Float16)(e[j] * inv);
        *(half8*)&S[base + k0] = o;
    }
}

// ---------------------------------------------------------------------------
// Kernel 4: O[b][q][e] = sum_{k<L} P[b][q][k] * Vt[b][e][k] for q<L;
// mean_v[b][e] for q>=L.  64-row q-tiles; DOUBLE-BUFFERED staging: next
// tile's global_load_lds fly during current tile's ds_read+MFMA; the next
// barrier's vmcnt(0) is the only drain.
// ---------------------------------------------------------------------------
__global__ __launch_bounds__(256) void pv_kernel(
    const _Float16* __restrict__ P, const _Float16* __restrict__ vhT,
    const int* __restrict__ lens, const float* __restrict__ mean_v,
    float* __restrict__ out)
{
    const int b  = blockIdx.z;
    const int L  = lens[b];
    const int r0 = blockIdx.y * 64;    // q rows (64-row tiles)
    const int c0 = blockIdx.x * 128;   // e cols
    const int KT = (r0 < L) ? ((L + 31) >> 5) : 0;
    const _Float16* A  = P   + (size_t)b * NN * NN;
    const _Float16* Vh = vhT + (size_t)b * DD * NN;

    __shared__ __align__(16) _Float16 As[2][64 * 32];
    __shared__ __align__(16) _Float16 Bhs[2][128 * 32];

    const int tid  = threadIdx.x;
    const int lane = tid & 63;
    const int w    = tid >> 6;
    const int lr   = lane & 15;
    const int quad = lane >> 4;

    floatx4 zero; zero[0]=0.f; zero[1]=0.f; zero[2]=0.f; zero[3]=0.f;
    floatx4 acc[4][2];
    for (int i = 0; i < 4; ++i)
        for (int j = 0; j < 2; ++j) acc[i][j] = zero;

    if (KT > 0) {
        stage_tile64(A + (size_t)r0 * NN, NN, As[0], w, lane);
        stage_tile (Vh + (size_t)c0 * NN, NN, Bhs[0], w, lane);
    }
    for (int kt = 0; kt < KT; ++kt) {
        const int cur = kt & 1;
        __syncthreads();                       // drains loads into cur
        if (kt + 1 < KT) {                     // prefetch next into other buf
            stage_tile64(A + (size_t)r0 * NN + (kt + 1) * 32, NN, As[cur ^ 1], w, lane);
            stage_tile (Vh + (size_t)c0 * NN + (kt + 1) * 32, NN, Bhs[cur ^ 1], w, lane);
        }
        half8 a[4], bh[2];
        for (int mt = 0; mt < 4; ++mt) a[mt]  = frag(As[cur], mt * 16 + lr, quad);
        for (int nt = 0; nt < 2; ++nt) bh[nt] = frag(Bhs[cur], w * 32 + nt * 16 + lr, quad);
        for (int mt = 0; mt < 4; ++mt)
            for (int nt = 0; nt < 2; ++nt)
                acc[mt][nt] = __builtin_amdgcn_mfma_f32_16x16x32_f16(a[mt], bh[nt], acc[mt][nt], 0, 0, 0);
    }

    float mval[2];
    for (int nt = 0; nt < 2; ++nt)
        mval[nt] = mean_v[b * DD + c0 + w * 32 + nt * 16 + lr];

    for (int mt = 0; mt < 4; ++mt)
        for (int nt = 0; nt < 2; ++nt)
            for (int r = 0; r < 4; ++r) {
                int q = r0 + mt * 16 + quad * 4 + r;
                int e = c0 + w * 32 + nt * 16 + lr;
                float val = (q < L) ? acc[mt][nt][r] : mval[nt];
                out[((size_t)b * NN + q) * DD + e] = val;
            }
}

// ---------------------------------------------------------------------------
extern "C" void kernel_launch(void* const* d_in, const int* in_sizes, int n_in,
                              void* d_out, int out_size, void* d_ws, size_t ws_size,
                              hipStream_t stream) {
    const float* x    = (const float*)d_in[0];
    const int*   lens = (const int*)d_in[1];   // harness delivers integer inputs as int32
    const float* Wq   = (const float*)d_in[2];
    const float* bq   = (const float*)d_in[3];
    const float* Wk   = (const float*)d_in[4];
    const float* bk   = (const float*)d_in[5];
    const float* Wv   = (const float*)d_in[6];
    const float* bv   = (const float*)d_in[7];
    float* out = (float*)d_out;

    // workspace layout (128 MiB):
    //   0: qb (16M) | 16M: kb (16M) | 32M: vhT (16M)
    //   48M: mean_v (2K fp32=16KB) | 48M+64K: sx (16KB)
    //   64M: S (64M) — first ~18M overlaid by [xh 16M | wqh | wkh | wvh],
    //        dead before scores_kernel writes S (stream-ordered).
    char* ws = (char*)d_ws;
    const size_t MB = 1024 * 1024;
    _Float16* qb  = (_Float16*)(ws);
    _Float16* kb  = (_Float16*)(ws + 16 * MB);
    _Float16* vh  = (_Float16*)(ws + 32 * MB);
    float*    mv  = (float*)   (ws + 48 * MB);
    float*    sx  = (float*)   (ws + 48 * MB + 64 * 1024);
    _Float16* S   = (_Float16*)(ws + 64 * MB);
    _Float16* xh  = (_Float16*)(ws + 64 * MB);
    _Float16* wqh = (_Float16*)(ws + 80 * MB);
    _Float16* wkh = (_Float16*)(ws + 80 * MB + 512 * 1024);
    _Float16* wvh = (_Float16*)(ws + 81 * MB);

    hipMemsetAsync(sx, 0, BB * DD * sizeof(float), stream);
    prep_kernel  <<<8960, 256, 0, stream>>>(x, Wq, Wk, Wv, lens, xh, wqh, wkh, wvh);
    meanx_kernel <<<dim3(32, 8),     256, 0, stream>>>(x, sx);
    mvgemv_kernel<<<1024,            256, 0, stream>>>(Wv, bv, sx, mv);
    projqk_kernel<<<dim3(4, 128, 2), 256, 0, stream>>>(xh, wqh, wkh, bq, bk, lens, qb, kb);
    projv_kernel <<<dim3(16, 4, 8),  256, 0, stream>>>(xh, wvh, bv, lens, vh);
    scores_kernel<<<dim3(16, 16, 8), 256, 0, stream>>>(qb, kb, lens, S);
    softmax_kernel<<<dim3(2048, 8),  256, 0, stream>>>(S, lens);
    pv_kernel    <<<dim3(4, 32, 8),  256, 0, stream>>>(S, vh, lens, mv, out);
}